// Round 1
// baseline (451.185 us; speedup 1.0000x reference)
//
#include <hip/hip_runtime.h>
#include <hip/hip_bf16.h>

#define DIM   384
#define SEQ   2048
#define BATCH 8
#define NHEAD 6
#define HD    64
#define MLPD  1536
#define MTOT  (BATCH*SEQ)   // 16384 rows

typedef __attribute__((ext_vector_type(8))) short bf16x8;
typedef __attribute__((ext_vector_type(4))) float f32x4;

static __device__ __forceinline__ float bf2f(unsigned short u){
    union { float f; unsigned int i; } v; v.i = ((unsigned int)u) << 16; return v.f;
}
static __device__ __forceinline__ unsigned short f2bf(float f){
    union { float f; unsigned int i; } v; v.f = f;
    unsigned int r = v.i + 0x7fffu + ((v.i >> 16) & 1u);
    return (unsigned short)(r >> 16);
}

// ---------------- weight transpose + cast: W[K][N] f32 -> Wt[N][K] bf16 ----------------
__global__ void wt_kernel(const float* __restrict__ W, unsigned short* __restrict__ Wt,
                          int K, int N){
    int idx = blockIdx.x * 256 + threadIdx.x;
    if (idx >= K * N) return;
    int n = idx / K, k = idx - n * K;
    Wt[idx] = f2bf(W[(size_t)k * N + n]);
}

// ---------------- layernorm: x f32 [rows][384] -> bf16 out ----------------
__global__ __launch_bounds__(256) void ln_kernel(const float* __restrict__ x,
                                                 const float* __restrict__ g,
                                                 const float* __restrict__ b,
                                                 unsigned short* __restrict__ out){
    int row  = blockIdx.x * 4 + (threadIdx.x >> 6);
    int lane = threadIdx.x & 63;
    const float* xr = x + (size_t)row * DIM;
    float v[6];
#pragma unroll
    for (int p = 0; p < 3; p++){
        float2 t = *(const float2*)(xr + lane * 2 + p * 128);
        v[2*p] = t.x; v[2*p+1] = t.y;
    }
    float s = 0.f, sq = 0.f;
#pragma unroll
    for (int i = 0; i < 6; i++){ s += v[i]; sq += v[i] * v[i]; }
#pragma unroll
    for (int off = 1; off < 64; off <<= 1){
        s  += __shfl_xor(s, off);
        sq += __shfl_xor(sq, off);
    }
    float mu   = s * (1.0f / DIM);
    float var  = sq * (1.0f / DIM) - mu * mu;
    float rstd = rsqrtf(var + 1e-5f);
    unsigned short* orow = out + (size_t)row * DIM;
#pragma unroll
    for (int p = 0; p < 3; p++){
        int c = lane * 2 + p * 128;
        float h0 = (v[2*p]   - mu) * rstd * g[c]   + b[c];
        float h1 = (v[2*p+1] - mu) * rstd * g[c+1] + b[c+1];
        unsigned int pk = (unsigned int)f2bf(h0) | ((unsigned int)f2bf(h1) << 16);
        *(unsigned int*)(orow + c) = pk;
    }
}

// ---------------- GEMM: C[M][N] = A[M][K] * Wt[N][K]^T, fused epilogues ----------------
// EPI 0: qkv scatter -> q/k [B,H,N,64] bf16, v transposed [B,H,64,N] bf16 (+bias)
// EPI 1: outf = resid + acc + bias (f32)
// EPI 2: outb = gelu(acc + bias) (bf16, exact erf gelu)
template<int EPI>
__global__ __launch_bounds__(256) void gemm_kernel(
    const unsigned short* __restrict__ A, const unsigned short* __restrict__ Bt,
    const float* __restrict__ bias, int K, int N,
    const float* __restrict__ resid, float* __restrict__ outf,
    unsigned short* __restrict__ outb,
    unsigned short* __restrict__ qb, unsigned short* __restrict__ kb2,
    unsigned short* __restrict__ vb)
{
    __shared__ __align__(16) unsigned short As[128][40];  // +8 pad: 2-way conflicts only
    __shared__ __align__(16) unsigned short Bs[128][40];
    int t = threadIdx.x;
    int wid = t >> 6, lane = t & 63, quad = lane >> 4, l15 = lane & 15;
    int wr = wid >> 1, wc = wid & 1;
    int row0 = blockIdx.y * 128, col0 = blockIdx.x * 128;

    f32x4 acc[4][4];
    f32x4 zz = {0.f, 0.f, 0.f, 0.f};
#pragma unroll
    for (int i = 0; i < 4; i++)
#pragma unroll
        for (int j = 0; j < 4; j++) acc[i][j] = zz;

    for (int k0 = 0; k0 < K; k0 += 32){
        __syncthreads();
#pragma unroll
        for (int i = 0; i < 2; i++){
            int id = t + i * 256;
            int r = id >> 2, c8 = (id & 3) * 8;
            uint4 a = *(const uint4*)(A  + (size_t)(row0 + r) * K + k0 + c8);
            *(uint4*)(&As[r][c8]) = a;
            uint4 bb = *(const uint4*)(Bt + (size_t)(col0 + r) * K + k0 + c8);
            *(uint4*)(&Bs[r][c8]) = bb;
        }
        __syncthreads();
        bf16x8 af[4], bf[4];
#pragma unroll
        for (int i = 0; i < 4; i++) af[i] = *(const bf16x8*)(&As[wr*64 + i*16 + l15][quad*8]);
#pragma unroll
        for (int j = 0; j < 4; j++) bf[j] = *(const bf16x8*)(&Bs[wc*64 + j*16 + l15][quad*8]);
#pragma unroll
        for (int i = 0; i < 4; i++)
#pragma unroll
            for (int j = 0; j < 4; j++)
                acc[i][j] = __builtin_amdgcn_mfma_f32_16x16x32_bf16(af[i], bf[j], acc[i][j], 0, 0, 0);
    }

#pragma unroll
    for (int i = 0; i < 4; i++){
#pragma unroll
        for (int j = 0; j < 4; j++){
            int gr0 = row0 + wr*64 + i*16 + quad*4;
            int gc  = col0 + wc*64 + j*16 + l15;
            float bia = bias[gc];
#pragma unroll
            for (int r = 0; r < 4; r++){
                int gr = gr0 + r;
                float val = acc[i][j][r] + bia;
                if (EPI == 1){
                    outf[(size_t)gr * N + gc] = resid[(size_t)gr * N + gc] + val;
                } else if (EPI == 2){
                    float ge = 0.5f * val * (1.0f + erff(val * 0.70710678f));
                    outb[(size_t)gr * N + gc] = f2bf(ge);
                } else {
                    int trip = gc / 384, rem = gc - trip * 384;
                    int head = rem >> 6, d = rem & 63;
                    int bidx = gr >> 11, ns = gr & 2047;
                    int bh = bidx * NHEAD + head;
                    if (trip == 0)      qb [((size_t)bh * SEQ + ns) * 64 + d] = f2bf(val);
                    else if (trip == 1) kb2[((size_t)bh * SEQ + ns) * 64 + d] = f2bf(val);
                    else                vb [((size_t)bh * 64 + d) * SEQ + ns] = f2bf(val);
                }
            }
        }
    }
}

// ---------------- flash attention: Q,K [B,H,N,64] bf16, Vt [B,H,64,N] bf16 ----------------
// grid (SEQ/64, B*H), 256 threads = 4 waves x 16 q-rows each; out bf16 [M][384]
__global__ __launch_bounds__(256) void attn_kernel(const unsigned short* __restrict__ Q,
                                                   const unsigned short* __restrict__ Kb,
                                                   const unsigned short* __restrict__ Vt,
                                                   unsigned short* __restrict__ O){
    __shared__ __align__(16) unsigned short Ks[64 * 64];   // [kv][d], 16B-chunk XOR swizzle
    __shared__ __align__(16) unsigned short Vs[64 * 64];   // [d][kv], same swizzle
    __shared__ __align__(16) unsigned short Ps[4][16 * 64]; // per-wave P, [q][kv], swizzled

    int bh = blockIdx.y, qt = blockIdx.x;
    int t = threadIdx.x, wid = t >> 6, lane = t & 63, quad = lane >> 4, l15 = lane & 15;
    int q0 = qt * 64 + wid * 16;
    const unsigned short* Qp = Q  + (size_t)bh * SEQ * 64;
    const unsigned short* Kp = Kb + (size_t)bh * SEQ * 64;
    const unsigned short* Vp = Vt + (size_t)bh * 64 * SEQ;

    // load + pre-scale Q fragments (A-layout: m=l15, k=c*32+quad*8+j)
    bf16x8 qf[2];
#pragma unroll
    for (int c = 0; c < 2; c++){
        union { uint4 u; unsigned short s[8]; } cv;
        cv.u = *(const uint4*)(Qp + (size_t)(q0 + l15) * 64 + c * 32 + quad * 8);
        bf16x8 f;
#pragma unroll
        for (int j = 0; j < 8; j++) f[j] = (short)f2bf(bf2f(cv.s[j]) * 0.125f);
        qf[c] = f;
    }

    float mi[4], li[4];
    f32x4 oacc[4];
    f32x4 zz = {0.f, 0.f, 0.f, 0.f};
#pragma unroll
    for (int r = 0; r < 4; r++){ mi[r] = -1e30f; li[r] = 0.f; }
#pragma unroll
    for (int dn = 0; dn < 4; dn++) oacc[dn] = zz;

    for (int kt = 0; kt < SEQ / 64; kt++){
        __syncthreads();
#pragma unroll
        for (int i = 0; i < 2; i++){
            int id = t + i * 256;
            int r = id >> 3, c8 = id & 7;
            uint4 kd = *(const uint4*)(Kp + (size_t)(kt * 64 + r) * 64 + c8 * 8);
            *(uint4*)(&Ks[r * 64 + ((c8 ^ (r & 7)) * 8)]) = kd;
            uint4 vd = *(const uint4*)(Vp + (size_t)r * SEQ + kt * 64 + c8 * 8);
            *(uint4*)(&Vs[r * 64 + ((c8 ^ (r & 7)) * 8)]) = vd;
        }
        __syncthreads();

        // S = Q K^T for 4 kv-subtiles of 16
        f32x4 s[4];
#pragma unroll
        for (int n = 0; n < 4; n++){
            int kv = n * 16 + l15;
            bf16x8 kf0 = *(const bf16x8*)(&Ks[kv * 64 + ((quad       ^ (kv & 7)) * 8)]);
            bf16x8 kf1 = *(const bf16x8*)(&Ks[kv * 64 + (((4 + quad) ^ (kv & 7)) * 8)]);
            f32x4 z = zz;
            z = __builtin_amdgcn_mfma_f32_16x16x32_bf16(qf[0], kf0, z, 0, 0, 0);
            z = __builtin_amdgcn_mfma_f32_16x16x32_bf16(qf[1], kf1, z, 0, 0, 0);
            s[n] = z;
        }
        // online softmax (rows = quad*4+r, cols across 16 lanes x 4 subtiles)
        float mx[4];
#pragma unroll
        for (int r = 0; r < 4; r++)
            mx[r] = fmaxf(fmaxf(s[0][r], s[1][r]), fmaxf(s[2][r], s[3][r]));
#pragma unroll
        for (int off = 1; off < 16; off <<= 1)
#pragma unroll
            for (int r = 0; r < 4; r++) mx[r] = fmaxf(mx[r], __shfl_xor(mx[r], off));
        float al[4], rs[4];
#pragma unroll
        for (int r = 0; r < 4; r++){
            float mn = fmaxf(mi[r], mx[r]);
            al[r] = __expf(mi[r] - mn);
            mi[r] = mn;
            rs[r] = 0.f;
        }
        unsigned short* P = &Ps[wid][0];
#pragma unroll
        for (int n = 0; n < 4; n++){
#pragma unroll
            for (int r = 0; r < 4; r++){
                float p = __expf(s[n][r] - mi[r]);
                rs[r] += p;
                int rr = quad * 4 + r, kv = n * 16 + l15;
                P[rr * 64 + (((kv >> 3) ^ (rr & 7)) * 8) + (kv & 7)] = f2bf(p);
            }
        }
#pragma unroll
        for (int off = 1; off < 16; off <<= 1)
#pragma unroll
            for (int r = 0; r < 4; r++) rs[r] += __shfl_xor(rs[r], off);
#pragma unroll
        for (int r = 0; r < 4; r++) li[r] = li[r] * al[r] + rs[r];
#pragma unroll
        for (int dn = 0; dn < 4; dn++)
#pragma unroll
            for (int r = 0; r < 4; r++) oacc[dn][r] *= al[r];

        asm volatile("s_waitcnt lgkmcnt(0)" ::: "memory");  // P writes -> reads, wave-private

        // O += P V  (A = P [q][kv], B = V^T fragments from Vs [d][kv])
#pragma unroll
        for (int c = 0; c < 2; c++){
            int chunk = c * 4 + quad;
            bf16x8 pf = *(const bf16x8*)(&P[l15 * 64 + ((chunk ^ (l15 & 7)) * 8)]);
#pragma unroll
            for (int dn = 0; dn < 4; dn++){
                int d = dn * 16 + l15;
                bf16x8 vf = *(const bf16x8*)(&Vs[d * 64 + ((chunk ^ (d & 7)) * 8)]);
                oacc[dn] = __builtin_amdgcn_mfma_f32_16x16x32_bf16(pf, vf, oacc[dn], 0, 0, 0);
            }
        }
    }

    int b = bh / NHEAD, h = bh - b * NHEAD;
#pragma unroll
    for (int dn = 0; dn < 4; dn++){
#pragma unroll
        for (int r = 0; r < 4; r++){
            float val = oacc[dn][r] / li[r];
            int row = b * SEQ + q0 + quad * 4 + r;
            int col = h * 64 + dn * 16 + l15;
            O[(size_t)row * DIM + col] = f2bf(val);
        }
    }
}

// ---------------- launcher ----------------
extern "C" void kernel_launch(void* const* d_in, const int* in_sizes, int n_in,
                              void* d_out, int out_size, void* d_ws, size_t ws_size,
                              hipStream_t stream){
    const float* x      = (const float*)d_in[0];
    const float* ln1_g  = (const float*)d_in[1];
    const float* ln1_b  = (const float*)d_in[2];
    const float* qkv_w  = (const float*)d_in[3];
    const float* qkv_b  = (const float*)d_in[4];
    const float* proj_w = (const float*)d_in[5];
    const float* proj_b = (const float*)d_in[6];
    const float* ln2_g  = (const float*)d_in[7];
    const float* ln2_b  = (const float*)d_in[8];
    const float* fc1_w  = (const float*)d_in[9];
    const float* fc1_b  = (const float*)d_in[10];
    const float* fc2_w  = (const float*)d_in[11];
    const float* fc2_b  = (const float*)d_in[12];
    float* out = (float*)d_out;

    char* p = (char*)d_ws;
    auto take = [&](size_t n){ char* r = p; p += (n + 255) & ~(size_t)255; return r; };
    unsigned short* wt_qkv = (unsigned short*)take((size_t)1152 * 384 * 2);
    unsigned short* wt_prj = (unsigned short*)take((size_t)384 * 384 * 2);
    unsigned short* wt_fc1 = (unsigned short*)take((size_t)1536 * 384 * 2);
    unsigned short* wt_fc2 = (unsigned short*)take((size_t)384 * 1536 * 2);
    unsigned short* rbig   = (unsigned short*)take((size_t)MTOT * 4 * DIM * 2); // h1|q|k|v, later hm
    unsigned short* h2     = (unsigned short*)take((size_t)MTOT * DIM * 2);
    float*          x1     = (float*)take((size_t)MTOT * DIM * 4);

    unsigned short* h1     = rbig;
    unsigned short* qb     = rbig + (size_t)MTOT * DIM;
    unsigned short* kb     = qb   + (size_t)MTOT * DIM;
    unsigned short* vb     = kb   + (size_t)MTOT * DIM;
    unsigned short* attn_o = rbig;   // reuses h1 (dead after QKV gemm)
    unsigned short* hm     = rbig;   // reuses h1+qkv (dead after proj), 16384x1536 bf16

    wt_kernel<<<dim3((1152*384 + 255)/256), 256, 0, stream>>>(qkv_w, wt_qkv, 384, 1152);
    wt_kernel<<<dim3((384*384  + 255)/256), 256, 0, stream>>>(proj_w, wt_prj, 384, 384);
    wt_kernel<<<dim3((1536*384 + 255)/256), 256, 0, stream>>>(fc1_w, wt_fc1, 384, 1536);
    wt_kernel<<<dim3((384*1536 + 255)/256), 256, 0, stream>>>(fc2_w, wt_fc2, 1536, 384);

    ln_kernel<<<dim3(MTOT/4), 256, 0, stream>>>(x, ln1_g, ln1_b, h1);
    gemm_kernel<0><<<dim3(9, 128), 256, 0, stream>>>(h1, wt_qkv, qkv_b, 384, 1152,
                                                     nullptr, nullptr, nullptr, qb, kb, vb);
    attn_kernel<<<dim3(SEQ/64, BATCH*NHEAD), 256, 0, stream>>>(qb, kb, vb, attn_o);
    gemm_kernel<1><<<dim3(3, 128), 256, 0, stream>>>(attn_o, wt_prj, proj_b, 384, 384,
                                                     x, x1, nullptr, nullptr, nullptr, nullptr);
    ln_kernel<<<dim3(MTOT/4), 256, 0, stream>>>(x1, ln2_g, ln2_b, h2);
    gemm_kernel<2><<<dim3(12, 128), 256, 0, stream>>>(h2, wt_fc1, fc1_b, 384, 1536,
                                                      nullptr, nullptr, hm, nullptr, nullptr, nullptr);
    gemm_kernel<1><<<dim3(3, 128), 256, 0, stream>>>(hm, wt_fc2, fc2_b, 1536, 384,
                                                     x1, out, nullptr, nullptr, nullptr, nullptr);
}

// Round 2
// 405.225 us; speedup vs baseline: 1.1134x; 1.1134x over previous
//
#include <hip/hip_runtime.h>
#include <hip/hip_bf16.h>

#define DIM   384
#define SEQ   2048
#define BATCH 8
#define NHEAD 6
#define HD    64
#define MLPD  1536
#define MTOT  (BATCH*SEQ)   // 16384 rows

typedef __attribute__((ext_vector_type(8))) short bf16x8;
typedef __attribute__((ext_vector_type(4))) float f32x4;

static __device__ __forceinline__ float bf2f(unsigned short u){
    union { float f; unsigned int i; } v; v.i = ((unsigned int)u) << 16; return v.f;
}
static __device__ __forceinline__ unsigned short f2bf(float f){
    union { float f; unsigned int i; } v; v.f = f;
    unsigned int r = v.i + 0x7fffu + ((v.i >> 16) & 1u);
    return (unsigned short)(r >> 16);
}
static __device__ __forceinline__ unsigned int asu(float f){
    union { float f; unsigned int i; } v; v.f = f; return v.i;
}

// ---------------- weight transpose + cast: W[K][N] f32 -> Wt[N][K] bf16 ----------------
__global__ void wt_kernel(const float* __restrict__ W, unsigned short* __restrict__ Wt,
                          int K, int N){
    int idx = blockIdx.x * 256 + threadIdx.x;
    if (idx >= K * N) return;
    int n = idx / K, k = idx - n * K;
    Wt[idx] = f2bf(W[(size_t)k * N + n]);
}

// ---------------- layernorm: x f32 [rows][384] -> bf16 out ----------------
__global__ __launch_bounds__(256) void ln_kernel(const float* __restrict__ x,
                                                 const float* __restrict__ g,
                                                 const float* __restrict__ b,
                                                 unsigned short* __restrict__ out){
    int row  = blockIdx.x * 4 + (threadIdx.x >> 6);
    int lane = threadIdx.x & 63;
    const float* xr = x + (size_t)row * DIM;
    float v[6];
#pragma unroll
    for (int p = 0; p < 3; p++){
        float2 t = *(const float2*)(xr + lane * 2 + p * 128);
        v[2*p] = t.x; v[2*p+1] = t.y;
    }
    float s = 0.f, sq = 0.f;
#pragma unroll
    for (int i = 0; i < 6; i++){ s += v[i]; sq += v[i] * v[i]; }
#pragma unroll
    for (int off = 1; off < 64; off <<= 1){
        s  += __shfl_xor(s, off);
        sq += __shfl_xor(sq, off);
    }
    float mu   = s * (1.0f / DIM);
    float var  = sq * (1.0f / DIM) - mu * mu;
    float rstd = rsqrtf(var + 1e-5f);
    unsigned short* orow = out + (size_t)row * DIM;
#pragma unroll
    for (int p = 0; p < 3; p++){
        int c = lane * 2 + p * 128;
        float h0 = (v[2*p]   - mu) * rstd * g[c]   + b[c];
        float h1 = (v[2*p+1] - mu) * rstd * g[c+1] + b[c+1];
        unsigned int pk = (unsigned int)f2bf(h0) | ((unsigned int)f2bf(h1) << 16);
        *(unsigned int*)(orow + c) = pk;
    }
}

// ---------------- GEMM: C[M][N] = A[M][K] * Wt[N][K]^T, fused epilogues ----------------
template<int EPI>
__global__ __launch_bounds__(256) void gemm_kernel(
    const unsigned short* __restrict__ A, const unsigned short* __restrict__ Bt,
    const float* __restrict__ bias, int K, int N,
    const float* __restrict__ resid, float* __restrict__ outf,
    unsigned short* __restrict__ outb,
    unsigned short* __restrict__ qb, unsigned short* __restrict__ kb2,
    unsigned short* __restrict__ vb)
{
    __shared__ __align__(16) unsigned short As[128][40];  // +8 pad: 2-way conflicts only
    __shared__ __align__(16) unsigned short Bs[128][40];
    int t = threadIdx.x;
    int wid = t >> 6, lane = t & 63, quad = lane >> 4, l15 = lane & 15;
    int wr = wid >> 1, wc = wid & 1;
    int row0 = blockIdx.y * 128, col0 = blockIdx.x * 128;

    f32x4 acc[4][4];
    f32x4 zz = {0.f, 0.f, 0.f, 0.f};
#pragma unroll
    for (int i = 0; i < 4; i++)
#pragma unroll
        for (int j = 0; j < 4; j++) acc[i][j] = zz;

    for (int k0 = 0; k0 < K; k0 += 32){
        __syncthreads();
#pragma unroll
        for (int i = 0; i < 2; i++){
            int id = t + i * 256;
            int r = id >> 2, c8 = (id & 3) * 8;
            uint4 a = *(const uint4*)(A  + (size_t)(row0 + r) * K + k0 + c8);
            *(uint4*)(&As[r][c8]) = a;
            uint4 bb = *(const uint4*)(Bt + (size_t)(col0 + r) * K + k0 + c8);
            *(uint4*)(&Bs[r][c8]) = bb;
        }
        __syncthreads();
        bf16x8 af[4], bf[4];
#pragma unroll
        for (int i = 0; i < 4; i++) af[i] = *(const bf16x8*)(&As[wr*64 + i*16 + l15][quad*8]);
#pragma unroll
        for (int j = 0; j < 4; j++) bf[j] = *(const bf16x8*)(&Bs[wc*64 + j*16 + l15][quad*8]);
#pragma unroll
        for (int i = 0; i < 4; i++)
#pragma unroll
            for (int j = 0; j < 4; j++)
                acc[i][j] = __builtin_amdgcn_mfma_f32_16x16x32_bf16(af[i], bf[j], acc[i][j], 0, 0, 0);
    }

#pragma unroll
    for (int i = 0; i < 4; i++){
#pragma unroll
        for (int j = 0; j < 4; j++){
            int gr0 = row0 + wr*64 + i*16 + quad*4;
            int gc  = col0 + wc*64 + j*16 + l15;
            float bia = bias[gc];
#pragma unroll
            for (int r = 0; r < 4; r++){
                int gr = gr0 + r;
                float val = acc[i][j][r] + bia;
                if (EPI == 1){
                    outf[(size_t)gr * N + gc] = resid[(size_t)gr * N + gc] + val;
                } else if (EPI == 2){
                    float ge = 0.5f * val * (1.0f + erff(val * 0.70710678f));
                    outb[(size_t)gr * N + gc] = f2bf(ge);
                } else {
                    int trip = gc / 384, rem = gc - trip * 384;
                    int head = rem >> 6, d = rem & 63;
                    int bidx = gr >> 11, ns = gr & 2047;
                    int bh = bidx * NHEAD + head;
                    if (trip == 0)      qb [((size_t)bh * SEQ + ns) * 64 + d] = f2bf(val);
                    else if (trip == 1) kb2[((size_t)bh * SEQ + ns) * 64 + d] = f2bf(val);
                    else                vb [((size_t)bh * 64 + d) * SEQ + ns] = f2bf(val);
                }
            }
        }
    }
}

// ---------------- flash attention v2 (S^T formulation) ----------------
// Q,K [B,H,N,64] bf16, Vt [B,H,64,N] bf16; out bf16 [M][384].
// grid (SEQ/128, B*H), 256 thr = 4 waves x 32 q-rows. Per-lane q = l15 (one row!):
// S^T = K*Q^T (C-layout: col=q, row=kv), softmax in-lane + 2 shfl, P packed
// b64 -> LDS [q][kv] (chunk-XOR swizzle), O^T = V^T * P^T.
__global__ __launch_bounds__(256) void attn_kernel(const unsigned short* __restrict__ Q,
                                                   const unsigned short* __restrict__ Kb,
                                                   const unsigned short* __restrict__ Vt,
                                                   unsigned short* __restrict__ O){
    __shared__ __align__(16) unsigned short Ks[64 * 64];    // [kv][d], 16B-chunk XOR swizzle
    __shared__ __align__(16) unsigned short Vs[64 * 64];    // [d][kv], same swizzle
    __shared__ __align__(16) unsigned short Ps[4][32 * 64]; // per-wave P [q][kv], swizzled

    int bh = blockIdx.y, qt = blockIdx.x;
    int t = threadIdx.x, wid = t >> 6, lane = t & 63, quad = lane >> 4, l15 = lane & 15;
    int l7 = l15 & 7;
    int q0 = qt * 128 + wid * 32;
    const unsigned short* Qp = Q  + (size_t)bh * SEQ * 64;
    const unsigned short* Kp = Kb + (size_t)bh * SEQ * 64;
    const unsigned short* Vp = Vt + (size_t)bh * 64 * SEQ;

    // Q fragments, pre-scaled by (1/8)*log2(e) so softmax runs in exp2 domain.
    // Same per-lane data serves as the MFMA B-operand (n=l15, k=quad*8+j).
    const float QSCALE = 0.125f * 1.44269504f;
    bf16x8 qf[2][2];
#pragma unroll
    for (int h = 0; h < 2; h++){
#pragma unroll
        for (int c = 0; c < 2; c++){
            union { uint4 u; unsigned short s[8]; } cv;
            cv.u = *(const uint4*)(Qp + (size_t)(q0 + h*16 + l15) * 64 + c * 32 + quad * 8);
            bf16x8 f;
#pragma unroll
            for (int j = 0; j < 8; j++) f[j] = (short)f2bf(bf2f(cv.s[j]) * QSCALE);
            qf[h][c] = f;
        }
    }

    float mi[2], li[2];
    f32x4 oacc[2][4];
    f32x4 zz = {0.f, 0.f, 0.f, 0.f};
#pragma unroll
    for (int h = 0; h < 2; h++){ mi[h] = -1e30f; li[h] = 0.f; }
#pragma unroll
    for (int h = 0; h < 2; h++)
#pragma unroll
        for (int dn = 0; dn < 4; dn++) oacc[h][dn] = zz;

    unsigned short* P = &Ps[wid][0];

    for (int kt = 0; kt < SEQ / 64; kt++){
        __syncthreads();
#pragma unroll
        for (int i = 0; i < 2; i++){
            int id = t + i * 256;
            int r = id >> 3, c8 = id & 7;
            uint4 kd = *(const uint4*)(Kp + (size_t)(kt * 64 + r) * 64 + c8 * 8);
            *(uint4*)(&Ks[r * 64 + ((c8 ^ (r & 7)) * 8)]) = kd;
            uint4 vd = *(const uint4*)(Vp + (size_t)r * SEQ + kt * 64 + c8 * 8);
            *(uint4*)(&Vs[r * 64 + ((c8 ^ (r & 7)) * 8)]) = vd;
        }
        __syncthreads();

        // S^T[kv][q] per 16-kv subtile n: A = K-frag, B = Q-frag (reused across q-halves)
        f32x4 st[2][4];
#pragma unroll
        for (int n = 0; n < 4; n++){
            int kv = n * 16 + l15;
            bf16x8 kf0 = *(const bf16x8*)(&Ks[kv * 64 + ((quad       ^ l7) * 8)]);
            bf16x8 kf1 = *(const bf16x8*)(&Ks[kv * 64 + (((4 + quad) ^ l7) * 8)]);
#pragma unroll
            for (int h = 0; h < 2; h++){
                f32x4 z = __builtin_amdgcn_mfma_f32_16x16x32_bf16(kf0, qf[h][0], zz, 0, 0, 0);
                st[h][n] = __builtin_amdgcn_mfma_f32_16x16x32_bf16(kf1, qf[h][1], z, 0, 0, 0);
            }
        }

        // online softmax: lane owns ONE q-row (l15) -> in-lane reduce + 2 shuffles
#pragma unroll
        for (int h = 0; h < 2; h++){
            float mx = st[h][0][0];
#pragma unroll
            for (int n = 0; n < 4; n++)
#pragma unroll
                for (int r = 0; r < 4; r++) mx = fmaxf(mx, st[h][n][r]);
            mx = fmaxf(mx, __shfl_xor(mx, 16));
            mx = fmaxf(mx, __shfl_xor(mx, 32));
            float mn = fmaxf(mi[h], mx);
            float al = __builtin_amdgcn_exp2f(mi[h] - mn);
            mi[h] = mn;
            float rs = 0.f;
            int qloc = h * 16 + l15;
#pragma unroll
            for (int n = 0; n < 4; n++){
                float p0 = __builtin_amdgcn_exp2f(st[h][n][0] - mn);
                float p1 = __builtin_amdgcn_exp2f(st[h][n][1] - mn);
                float p2 = __builtin_amdgcn_exp2f(st[h][n][2] - mn);
                float p3 = __builtin_amdgcn_exp2f(st[h][n][3] - mn);
                rs += (p0 + p1) + (p2 + p3);
                // pack 4 bf16 (round-half-up) via v_perm, one ds_write_b64
                unsigned int w0 = __builtin_amdgcn_perm(asu(p1) + 0x8000u, asu(p0) + 0x8000u, 0x07060302u);
                unsigned int w1 = __builtin_amdgcn_perm(asu(p3) + 0x8000u, asu(p2) + 0x8000u, 0x07060302u);
                int chunk = n * 2 + (quad >> 1);
                uint2* dst = (uint2*)(P + qloc * 64 + ((chunk ^ l7) * 8) + (quad & 1) * 4);
                *dst = make_uint2(w0, w1);
            }
            rs += __shfl_xor(rs, 16);
            rs += __shfl_xor(rs, 32);
            li[h] = li[h] * al + rs;
#pragma unroll
            for (int dn = 0; dn < 4; dn++)
#pragma unroll
                for (int r = 0; r < 4; r++) oacc[h][dn][r] *= al;
        }

        asm volatile("s_waitcnt lgkmcnt(0)" ::: "memory");  // wave-private P: writes -> reads

        // O^T[d][q] += V^T * P^T : A = V-frag (rows d), B = P-frag (cols q)
#pragma unroll
        for (int c = 0; c < 2; c++){
            int chunk = c * 4 + quad;
            bf16x8 pf[2];
#pragma unroll
            for (int h = 0; h < 2; h++)
                pf[h] = *(const bf16x8*)(P + (h*16 + l15) * 64 + ((chunk ^ l7) * 8));
#pragma unroll
            for (int dn = 0; dn < 4; dn++){
                int d = dn * 16 + l15;
                bf16x8 vf = *(const bf16x8*)(&Vs[d * 64 + ((chunk ^ (d & 7)) * 8)]);
                oacc[0][dn] = __builtin_amdgcn_mfma_f32_16x16x32_bf16(vf, pf[0], oacc[0][dn], 0, 0, 0);
                oacc[1][dn] = __builtin_amdgcn_mfma_f32_16x16x32_bf16(vf, pf[1], oacc[1][dn], 0, 0, 0);
            }
        }
    }

    int b = bh / NHEAD, hh = bh - b * NHEAD;
#pragma unroll
    for (int h = 0; h < 2; h++){
        float rd = 1.0f / li[h];
        size_t row = (size_t)(b * SEQ + q0 + h*16 + l15);
#pragma unroll
        for (int dn = 0; dn < 4; dn++){
            float v0 = oacc[h][dn][0] * rd, v1 = oacc[h][dn][1] * rd;
            float v2 = oacc[h][dn][2] * rd, v3 = oacc[h][dn][3] * rd;
            unsigned int w0 = (unsigned int)f2bf(v0) | ((unsigned int)f2bf(v1) << 16);
            unsigned int w1 = (unsigned int)f2bf(v2) | ((unsigned int)f2bf(v3) << 16);
            *(uint2*)(O + row * DIM + hh * 64 + dn * 16 + quad * 4) = make_uint2(w0, w1);
        }
    }
}

// ---------------- launcher ----------------
extern "C" void kernel_launch(void* const* d_in, const int* in_sizes, int n_in,
                              void* d_out, int out_size, void* d_ws, size_t ws_size,
                              hipStream_t stream){
    const float* x      = (const float*)d_in[0];
    const float* ln1_g  = (const float*)d_in[1];
    const float* ln1_b  = (const float*)d_in[2];
    const float* qkv_w  = (const float*)d_in[3];
    const float* qkv_b  = (const float*)d_in[4];
    const float* proj_w = (const float*)d_in[5];
    const float* proj_b = (const float*)d_in[6];
    const float* ln2_g  = (const float*)d_in[7];
    const float* ln2_b  = (const float*)d_in[8];
    const float* fc1_w  = (const float*)d_in[9];
    const float* fc1_b  = (const float*)d_in[10];
    const float* fc2_w  = (const float*)d_in[11];
    const float* fc2_b  = (const float*)d_in[12];
    float* out = (float*)d_out;

    char* p = (char*)d_ws;
    auto take = [&](size_t n){ char* r = p; p += (n + 255) & ~(size_t)255; return r; };
    unsigned short* wt_qkv = (unsigned short*)take((size_t)1152 * 384 * 2);
    unsigned short* wt_prj = (unsigned short*)take((size_t)384 * 384 * 2);
    unsigned short* wt_fc1 = (unsigned short*)take((size_t)1536 * 384 * 2);
    unsigned short* wt_fc2 = (unsigned short*)take((size_t)384 * 1536 * 2);
    unsigned short* rbig   = (unsigned short*)take((size_t)MTOT * 4 * DIM * 2); // h1|q|k|v, later hm
    unsigned short* h2     = (unsigned short*)take((size_t)MTOT * DIM * 2);
    float*          x1     = (float*)take((size_t)MTOT * DIM * 4);

    unsigned short* h1     = rbig;
    unsigned short* qb     = rbig + (size_t)MTOT * DIM;
    unsigned short* kb     = qb   + (size_t)MTOT * DIM;
    unsigned short* vb     = kb   + (size_t)MTOT * DIM;
    unsigned short* attn_o = rbig;   // reuses h1 (dead after QKV gemm)
    unsigned short* hm     = rbig;   // reuses h1+qkv (dead after proj), 16384x1536 bf16

    wt_kernel<<<dim3((1152*384 + 255)/256), 256, 0, stream>>>(qkv_w, wt_qkv, 384, 1152);
    wt_kernel<<<dim3((384*384  + 255)/256), 256, 0, stream>>>(proj_w, wt_prj, 384, 384);
    wt_kernel<<<dim3((1536*384 + 255)/256), 256, 0, stream>>>(fc1_w, wt_fc1, 384, 1536);
    wt_kernel<<<dim3((384*1536 + 255)/256), 256, 0, stream>>>(fc2_w, wt_fc2, 1536, 384);

    ln_kernel<<<dim3(MTOT/4), 256, 0, stream>>>(x, ln1_g, ln1_b, h1);
    gemm_kernel<0><<<dim3(9, 128), 256, 0, stream>>>(h1, wt_qkv, qkv_b, 384, 1152,
                                                     nullptr, nullptr, nullptr, qb, kb, vb);
    attn_kernel<<<dim3(SEQ/128, BATCH*NHEAD), 256, 0, stream>>>(qb, kb, vb, attn_o);
    gemm_kernel<1><<<dim3(3, 128), 256, 0, stream>>>(attn_o, wt_prj, proj_b, 384, 384,
                                                     x, x1, nullptr, nullptr, nullptr, nullptr);
    ln_kernel<<<dim3(MTOT/4), 256, 0, stream>>>(x1, ln2_g, ln2_b, h2);
    gemm_kernel<2><<<dim3(12, 128), 256, 0, stream>>>(h2, wt_fc1, fc1_b, 384, 1536,
                                                      nullptr, nullptr, hm, nullptr, nullptr, nullptr);
    gemm_kernel<1><<<dim3(3, 128), 256, 0, stream>>>(hm, wt_fc2, fc2_b, 1536, 384,
                                                     x1, out, nullptr, nullptr, nullptr, nullptr);
}

// Round 3
// 385.222 us; speedup vs baseline: 1.1712x; 1.0519x over previous
//
#include <hip/hip_runtime.h>
#include <hip/hip_bf16.h>

#define DIM   384
#define SEQ   2048
#define BATCH 8
#define NHEAD 6
#define HD    64
#define MLPD  1536
#define MTOT  (BATCH*SEQ)   // 16384 rows

typedef __attribute__((ext_vector_type(8))) short bf16x8;
typedef __attribute__((ext_vector_type(4))) float f32x4;

static __device__ __forceinline__ float bf2f(unsigned short u){
    union { float f; unsigned int i; } v; v.i = ((unsigned int)u) << 16; return v.f;
}
static __device__ __forceinline__ unsigned short f2bf(float f){
    union { float f; unsigned int i; } v; v.f = f;
    unsigned int r = v.i + 0x7fffu + ((v.i >> 16) & 1u);
    return (unsigned short)(r >> 16);
}
static __device__ __forceinline__ unsigned int asu(float f){
    union { float f; unsigned int i; } v; v.f = f; return v.i;
}
// async global->LDS, 16B per lane; LDS dst = wave-uniform base + lane*16
static __device__ __forceinline__ void gload_lds16(const unsigned short* g, unsigned short* l){
    __builtin_amdgcn_global_load_lds(
        (__attribute__((address_space(1))) void*)(g),
        (__attribute__((address_space(3))) void*)(l), 16, 0, 0);
}

// ---------------- merged weight transpose + cast, LDS-tiled ----------------
// W[K][N] f32 -> Wt[N][K] bf16 for all four weights; 64x64 tiles.
__global__ __launch_bounds__(256) void wt_all_kernel(
    const float* __restrict__ qkv_w, const float* __restrict__ proj_w,
    const float* __restrict__ fc1_w, const float* __restrict__ fc2_w,
    unsigned short* __restrict__ o_qkv, unsigned short* __restrict__ o_prj,
    unsigned short* __restrict__ o_fc1, unsigned short* __restrict__ o_fc2)
{
    __shared__ float tile[64][68];
    int bid = blockIdx.x;
    const float* W; unsigned short* Wt; int K, N, tk, tn;
    if (bid < 108)      { W = qkv_w; Wt = o_qkv; K = 384;  N = 1152; tk = bid/18;        tn = bid%18; }
    else if (bid < 144) { W = proj_w; Wt = o_prj; K = 384;  N = 384;  tk = (bid-108)/6;  tn = (bid-108)%6; }
    else if (bid < 288) { W = fc1_w; Wt = o_fc1; K = 384;  N = 1536; tk = (bid-144)/24; tn = (bid-144)%24; }
    else                { W = fc2_w; Wt = o_fc2; K = 1536; N = 384;  tk = (bid-288)/6;  tn = (bid-288)%6; }
    int t = threadIdx.x;
    int lr = t >> 4, lc = (t & 15) * 4;
#pragma unroll
    for (int p = 0; p < 4; p++){
        float4 v = *(const float4*)(W + (size_t)(tk*64 + p*16 + lr) * N + tn*64 + lc);
        *(float4*)&tile[p*16 + lr][lc] = v;   // row stride 272B (16B-aligned)
    }
    __syncthreads();
    int n = t >> 2, k0 = (t & 3) * 16;
    unsigned int w[8];
#pragma unroll
    for (int i = 0; i < 8; i++)
        w[i] = (unsigned int)f2bf(tile[k0 + 2*i][n]) | ((unsigned int)f2bf(tile[k0 + 2*i + 1][n]) << 16);
    unsigned short* dst = Wt + (size_t)(tn*64 + n) * K + tk*64 + k0;
    *(uint4*)(dst)     = make_uint4(w[0], w[1], w[2], w[3]);
    *(uint4*)(dst + 8) = make_uint4(w[4], w[5], w[6], w[7]);
}

// ---------------- layernorm: x f32 [rows][384] -> bf16 out ----------------
__global__ __launch_bounds__(256) void ln_kernel(const float* __restrict__ x,
                                                 const float* __restrict__ g,
                                                 const float* __restrict__ b,
                                                 unsigned short* __restrict__ out){
    int row  = blockIdx.x * 4 + (threadIdx.x >> 6);
    int lane = threadIdx.x & 63;
    const float* xr = x + (size_t)row * DIM;
    float v[6];
#pragma unroll
    for (int p = 0; p < 3; p++){
        float2 t = *(const float2*)(xr + lane * 2 + p * 128);
        v[2*p] = t.x; v[2*p+1] = t.y;
    }
    float s = 0.f, sq = 0.f;
#pragma unroll
    for (int i = 0; i < 6; i++){ s += v[i]; sq += v[i] * v[i]; }
#pragma unroll
    for (int off = 1; off < 64; off <<= 1){
        s  += __shfl_xor(s, off);
        sq += __shfl_xor(sq, off);
    }
    float mu   = s * (1.0f / DIM);
    float var  = sq * (1.0f / DIM) - mu * mu;
    float rstd = rsqrtf(var + 1e-5f);
    unsigned short* orow = out + (size_t)row * DIM;
#pragma unroll
    for (int p = 0; p < 3; p++){
        int c = lane * 2 + p * 128;
        float h0 = (v[2*p]   - mu) * rstd * g[c]   + b[c];
        float h1 = (v[2*p+1] - mu) * rstd * g[c+1] + b[c+1];
        unsigned int pk = (unsigned int)f2bf(h0) | ((unsigned int)f2bf(h1) << 16);
        *(unsigned int*)(orow + c) = pk;
    }
}

// ---------------- GEMM: C[M][N] = A[M][K] * Wt[N][K]^T, fused epilogues ----------------
// BK=64, async global_load_lds staging with global-side XOR chunk swizzle:
// LDS tile As[r][c_phys] = A[r][c_phys ^ (r&7)] (16B chunks), readers XOR back.
template<int EPI>
__global__ __launch_bounds__(256) void gemm_kernel(
    const unsigned short* __restrict__ A, const unsigned short* __restrict__ Bt,
    const float* __restrict__ bias, int K, int N,
    const float* __restrict__ resid, float* __restrict__ outf,
    unsigned short* __restrict__ outb,
    unsigned short* __restrict__ qb, unsigned short* __restrict__ kb2,
    unsigned short* __restrict__ vb)
{
    __shared__ __align__(16) unsigned short As[128 * 64];
    __shared__ __align__(16) unsigned short Bs[128 * 64];
    int t = threadIdx.x;
    int wid = t >> 6, lane = t & 63, quad = lane >> 4, l15 = lane & 15;
    int wr = wid >> 1, wc = wid & 1;
    int row0 = blockIdx.y * 128, col0 = blockIdx.x * 128;
    int sr = lane >> 3, sc = lane & 7;          // staging: 8 rows x 8 chunks per issue
    int scl = (sc ^ sr) * 8;                    // global-side swizzled chunk (shorts)

    const unsigned short* Ab = A  + (size_t)row0 * K;
    const unsigned short* Bb = Bt + (size_t)col0 * K;

    f32x4 acc[4][4];
    f32x4 zz = {0.f, 0.f, 0.f, 0.f};
#pragma unroll
    for (int i = 0; i < 4; i++)
#pragma unroll
        for (int j = 0; j < 4; j++) acc[i][j] = zz;

    for (int k0 = 0; k0 < K; k0 += 64){
        __syncthreads();
#pragma unroll
        for (int j = 0; j < 4; j++){
            int rb = wid * 32 + j * 8;          // wave-uniform base row
            gload_lds16(Ab + (size_t)(rb + sr) * K + k0 + scl, &As[rb * 64]);
            gload_lds16(Bb + (size_t)(rb + sr) * K + k0 + scl, &Bs[rb * 64]);
        }
        __syncthreads();                         // drains vmcnt(0) then barrier
#pragma unroll
        for (int kk = 0; kk < 2; kk++){
            bf16x8 af[4], bf[4];
#pragma unroll
            for (int i = 0; i < 4; i++){
                int r = wr*64 + i*16 + l15;
                af[i] = *(const bf16x8*)&As[r * 64 + (((kk*4 + quad) ^ (l15 & 7)) * 8)];
            }
#pragma unroll
            for (int j = 0; j < 4; j++){
                int r = wc*64 + j*16 + l15;
                bf[j] = *(const bf16x8*)&Bs[r * 64 + (((kk*4 + quad) ^ (l15 & 7)) * 8)];
            }
#pragma unroll
            for (int i = 0; i < 4; i++)
#pragma unroll
                for (int j = 0; j < 4; j++)
                    acc[i][j] = __builtin_amdgcn_mfma_f32_16x16x32_bf16(af[i], bf[j], acc[i][j], 0, 0, 0);
        }
    }

#pragma unroll
    for (int i = 0; i < 4; i++){
#pragma unroll
        for (int j = 0; j < 4; j++){
            int gr0 = row0 + wr*64 + i*16 + quad*4;
            int gc  = col0 + wc*64 + j*16 + l15;
            float bia = bias[gc];
#pragma unroll
            for (int r = 0; r < 4; r++){
                int gr = gr0 + r;
                float val = acc[i][j][r] + bia;
                if (EPI == 1){
                    outf[(size_t)gr * N + gc] = resid[(size_t)gr * N + gc] + val;
                } else if (EPI == 2){
                    float ge = 0.5f * val * (1.0f + erff(val * 0.70710678f));
                    outb[(size_t)gr * N + gc] = f2bf(ge);
                } else {
                    int trip = gc / 384, rem = gc - trip * 384;
                    int head = rem >> 6, d = rem & 63;
                    int bidx = gr >> 11, ns = gr & 2047;
                    int bh = bidx * NHEAD + head;
                    if (trip == 0)      qb [((size_t)bh * SEQ + ns) * 64 + d] = f2bf(val);
                    else if (trip == 1) kb2[((size_t)bh * SEQ + ns) * 64 + d] = f2bf(val);
                    else                vb [((size_t)bh * 64 + d) * SEQ + ns] = f2bf(val);
                }
            }
        }
    }
}

// ---------------- flash attention (S^T formulation) ----------------
__global__ __launch_bounds__(256) void attn_kernel(const unsigned short* __restrict__ Q,
                                                   const unsigned short* __restrict__ Kb,
                                                   const unsigned short* __restrict__ Vt,
                                                   unsigned short* __restrict__ O){
    __shared__ __align__(16) unsigned short Ks[64 * 64];    // [kv][d], 16B-chunk XOR swizzle
    __shared__ __align__(16) unsigned short Vs[64 * 64];    // [d][kv], same swizzle
    __shared__ __align__(16) unsigned short Ps[4][32 * 64]; // per-wave P [q][kv]

    int bh = blockIdx.y, qt = blockIdx.x;
    int t = threadIdx.x, wid = t >> 6, lane = t & 63, quad = lane >> 4, l15 = lane & 15;
    int l7 = l15 & 7;
    int q0 = qt * 128 + wid * 32;
    const unsigned short* Qp = Q  + (size_t)bh * SEQ * 64;
    const unsigned short* Kp = Kb + (size_t)bh * SEQ * 64;
    const unsigned short* Vp = Vt + (size_t)bh * 64 * SEQ;

    const float QSCALE = 0.125f * 1.44269504f;  // exp2 domain
    bf16x8 qf[2][2];
#pragma unroll
    for (int h = 0; h < 2; h++){
#pragma unroll
        for (int c = 0; c < 2; c++){
            union { uint4 u; unsigned short s[8]; } cv;
            cv.u = *(const uint4*)(Qp + (size_t)(q0 + h*16 + l15) * 64 + c * 32 + quad * 8);
            bf16x8 f;
#pragma unroll
            for (int j = 0; j < 8; j++) f[j] = (short)f2bf(bf2f(cv.s[j]) * QSCALE);
            qf[h][c] = f;
        }
    }

    float mi[2], li[2];
    f32x4 oacc[2][4];
    f32x4 zz = {0.f, 0.f, 0.f, 0.f};
#pragma unroll
    for (int h = 0; h < 2; h++){ mi[h] = -1e30f; li[h] = 0.f; }
#pragma unroll
    for (int h = 0; h < 2; h++)
#pragma unroll
        for (int dn = 0; dn < 4; dn++) oacc[h][dn] = zz;

    unsigned short* P = &Ps[wid][0];

    for (int kt = 0; kt < SEQ / 64; kt++){
        __syncthreads();
#pragma unroll
        for (int i = 0; i < 2; i++){
            int id = t + i * 256;
            int r = id >> 3, c8 = id & 7;
            uint4 kd = *(const uint4*)(Kp + (size_t)(kt * 64 + r) * 64 + c8 * 8);
            *(uint4*)(&Ks[r * 64 + ((c8 ^ (r & 7)) * 8)]) = kd;
            uint4 vd = *(const uint4*)(Vp + (size_t)r * SEQ + kt * 64 + c8 * 8);
            *(uint4*)(&Vs[r * 64 + ((c8 ^ (r & 7)) * 8)]) = vd;
        }
        __syncthreads();

        f32x4 st[2][4];
#pragma unroll
        for (int n = 0; n < 4; n++){
            int kv = n * 16 + l15;
            bf16x8 kf0 = *(const bf16x8*)(&Ks[kv * 64 + ((quad       ^ l7) * 8)]);
            bf16x8 kf1 = *(const bf16x8*)(&Ks[kv * 64 + (((4 + quad) ^ l7) * 8)]);
#pragma unroll
            for (int h = 0; h < 2; h++){
                f32x4 z = __builtin_amdgcn_mfma_f32_16x16x32_bf16(kf0, qf[h][0], zz, 0, 0, 0);
                st[h][n] = __builtin_amdgcn_mfma_f32_16x16x32_bf16(kf1, qf[h][1], z, 0, 0, 0);
            }
        }

#pragma unroll
        for (int h = 0; h < 2; h++){
            float mx = st[h][0][0];
#pragma unroll
            for (int n = 0; n < 4; n++)
#pragma unroll
                for (int r = 0; r < 4; r++) mx = fmaxf(mx, st[h][n][r]);
            mx = fmaxf(mx, __shfl_xor(mx, 16));
            mx = fmaxf(mx, __shfl_xor(mx, 32));
            // wave-uniform skip: rescale is an exact no-op when mx <= mi for all lanes
            if (__any(mx > mi[h])){
                float mn = fmaxf(mi[h], mx);
                float al = __builtin_amdgcn_exp2f(mi[h] - mn);
                mi[h] = mn;
                li[h] *= al;
#pragma unroll
                for (int dn = 0; dn < 4; dn++)
#pragma unroll
                    for (int r = 0; r < 4; r++) oacc[h][dn][r] *= al;
            }
            float mn = mi[h];
            float rs = 0.f;
            int qloc = h * 16 + l15;
            int pk = (qloc ^ (qloc >> 3)) & 7;   // decorrelate rows 8 apart (bank fix)
#pragma unroll
            for (int n = 0; n < 4; n++){
                float p0 = __builtin_amdgcn_exp2f(st[h][n][0] - mn);
                float p1 = __builtin_amdgcn_exp2f(st[h][n][1] - mn);
                float p2 = __builtin_amdgcn_exp2f(st[h][n][2] - mn);
                float p3 = __builtin_amdgcn_exp2f(st[h][n][3] - mn);
                rs += (p0 + p1) + (p2 + p3);
                unsigned int w0 = __builtin_amdgcn_perm(asu(p1) + 0x8000u, asu(p0) + 0x8000u, 0x07060302u);
                unsigned int w1 = __builtin_amdgcn_perm(asu(p3) + 0x8000u, asu(p2) + 0x8000u, 0x07060302u);
                int chunk = n * 2 + (quad >> 1);
                uint2* dst = (uint2*)(P + qloc * 64 + ((chunk ^ pk) * 8) + (quad & 1) * 4);
                *dst = make_uint2(w0, w1);
            }
            rs += __shfl_xor(rs, 16);
            rs += __shfl_xor(rs, 32);
            li[h] += rs;
        }

        asm volatile("s_waitcnt lgkmcnt(0)" ::: "memory");  // wave-private P: writes -> reads

#pragma unroll
        for (int c = 0; c < 2; c++){
            int chunk = c * 4 + quad;
            bf16x8 pf[2];
#pragma unroll
            for (int h = 0; h < 2; h++){
                int qr = h * 16 + l15;
                int pk = (qr ^ (qr >> 3)) & 7;
                pf[h] = *(const bf16x8*)(P + qr * 64 + ((chunk ^ pk) * 8));
            }
#pragma unroll
            for (int dn = 0; dn < 4; dn++){
                int d = dn * 16 + l15;
                bf16x8 vf = *(const bf16x8*)(&Vs[d * 64 + ((chunk ^ (d & 7)) * 8)]);
                oacc[0][dn] = __builtin_amdgcn_mfma_f32_16x16x32_bf16(vf, pf[0], oacc[0][dn], 0, 0, 0);
                oacc[1][dn] = __builtin_amdgcn_mfma_f32_16x16x32_bf16(vf, pf[1], oacc[1][dn], 0, 0, 0);
            }
        }
    }

    int b = bh / NHEAD, hh = bh - b * NHEAD;
#pragma unroll
    for (int h = 0; h < 2; h++){
        float rd = 1.0f / li[h];
        size_t row = (size_t)(b * SEQ + q0 + h*16 + l15);
#pragma unroll
        for (int dn = 0; dn < 4; dn++){
            float v0 = oacc[h][dn][0] * rd, v1 = oacc[h][dn][1] * rd;
            float v2 = oacc[h][dn][2] * rd, v3 = oacc[h][dn][3] * rd;
            unsigned int w0 = (unsigned int)f2bf(v0) | ((unsigned int)f2bf(v1) << 16);
            unsigned int w1 = (unsigned int)f2bf(v2) | ((unsigned int)f2bf(v3) << 16);
            *(uint2*)(O + row * DIM + hh * 64 + dn * 16 + quad * 4) = make_uint2(w0, w1);
        }
    }
}

// ---------------- launcher ----------------
extern "C" void kernel_launch(void* const* d_in, const int* in_sizes, int n_in,
                              void* d_out, int out_size, void* d_ws, size_t ws_size,
                              hipStream_t stream){
    const float* x      = (const float*)d_in[0];
    const float* ln1_g  = (const float*)d_in[1];
    const float* ln1_b  = (const float*)d_in[2];
    const float* qkv_w  = (const float*)d_in[3];
    const float* qkv_b  = (const float*)d_in[4];
    const float* proj_w = (const float*)d_in[5];
    const float* proj_b = (const float*)d_in[6];
    const float* ln2_g  = (const float*)d_in[7];
    const float* ln2_b  = (const float*)d_in[8];
    const float* fc1_w  = (const float*)d_in[9];
    const float* fc1_b  = (const float*)d_in[10];
    const float* fc2_w  = (const float*)d_in[11];
    const float* fc2_b  = (const float*)d_in[12];
    float* out = (float*)d_out;

    char* p = (char*)d_ws;
    auto take = [&](size_t n){ char* r = p; p += (n + 255) & ~(size_t)255; return r; };
    unsigned short* wt_qkv = (unsigned short*)take((size_t)1152 * 384 * 2);
    unsigned short* wt_prj = (unsigned short*)take((size_t)384 * 384 * 2);
    unsigned short* wt_fc1 = (unsigned short*)take((size_t)1536 * 384 * 2);
    unsigned short* wt_fc2 = (unsigned short*)take((size_t)384 * 1536 * 2);
    unsigned short* rbig   = (unsigned short*)take((size_t)MTOT * 4 * DIM * 2); // h1|q|k|v, later hm
    unsigned short* h2     = (unsigned short*)take((size_t)MTOT * DIM * 2);
    float*          x1     = (float*)take((size_t)MTOT * DIM * 4);

    unsigned short* h1     = rbig;
    unsigned short* qb     = rbig + (size_t)MTOT * DIM;
    unsigned short* kb     = qb   + (size_t)MTOT * DIM;
    unsigned short* vb     = kb   + (size_t)MTOT * DIM;
    unsigned short* attn_o = rbig;   // reuses h1 (dead after QKV gemm)
    unsigned short* hm     = rbig;   // reuses h1+qkv (dead after proj), 16384x1536 bf16

    wt_all_kernel<<<dim3(432), 256, 0, stream>>>(qkv_w, proj_w, fc1_w, fc2_w,
                                                 wt_qkv, wt_prj, wt_fc1, wt_fc2);
    ln_kernel<<<dim3(MTOT/4), 256, 0, stream>>>(x, ln1_g, ln1_b, h1);
    gemm_kernel<0><<<dim3(9, 128), 256, 0, stream>>>(h1, wt_qkv, qkv_b, 384, 1152,
                                                     nullptr, nullptr, nullptr, qb, kb, vb);
    attn_kernel<<<dim3(SEQ/128, BATCH*NHEAD), 256, 0, stream>>>(qb, kb, vb, attn_o);
    gemm_kernel<1><<<dim3(3, 128), 256, 0, stream>>>(attn_o, wt_prj, proj_b, 384, 384,
                                                     x, x1, nullptr, nullptr, nullptr, nullptr);
    ln_kernel<<<dim3(MTOT/4), 256, 0, stream>>>(x1, ln2_g, ln2_b, h2);
    gemm_kernel<2><<<dim3(12, 128), 256, 0, stream>>>(h2, wt_fc1, fc1_b, 384, 1536,
                                                      nullptr, nullptr, hm, nullptr, nullptr, nullptr);
    gemm_kernel<1><<<dim3(3, 128), 256, 0, stream>>>(hm, wt_fc2, fc2_b, 1536, 384,
                                                     x1, out, nullptr, nullptr, nullptr, nullptr);
}

// Round 4
// 361.224 us; speedup vs baseline: 1.2490x; 1.0664x over previous
//
#include <hip/hip_runtime.h>
#include <hip/hip_bf16.h>

#define DIM   384
#define SEQ   2048
#define BATCH 8
#define NHEAD 6
#define HD    64
#define MLPD  1536
#define MTOT  (BATCH*SEQ)   // 16384 rows

typedef __attribute__((ext_vector_type(8))) short bf16x8;
typedef __attribute__((ext_vector_type(4))) float f32x4;

static __device__ __forceinline__ float bf2f(unsigned short u){
    union { float f; unsigned int i; } v; v.i = ((unsigned int)u) << 16; return v.f;
}
static __device__ __forceinline__ unsigned short f2bf(float f){
    union { float f; unsigned int i; } v; v.f = f;
    unsigned int r = v.i + 0x7fffu + ((v.i >> 16) & 1u);
    return (unsigned short)(r >> 16);
}
static __device__ __forceinline__ unsigned int asu(float f){
    union { float f; unsigned int i; } v; v.f = f; return v.i;
}
// async global->LDS, 16B per lane; LDS dst = wave-uniform base + lane*16
static __device__ __forceinline__ void gload_lds16(const unsigned short* g, unsigned short* l){
    __builtin_amdgcn_global_load_lds(
        (__attribute__((address_space(1))) void*)(g),
        (__attribute__((address_space(3))) void*)(l), 16, 0, 0);
}

// ---------------- merged weight transpose + cast, LDS-tiled ----------------
__global__ __launch_bounds__(256) void wt_all_kernel(
    const float* __restrict__ qkv_w, const float* __restrict__ proj_w,
    const float* __restrict__ fc1_w, const float* __restrict__ fc2_w,
    unsigned short* __restrict__ o_qkv, unsigned short* __restrict__ o_prj,
    unsigned short* __restrict__ o_fc1, unsigned short* __restrict__ o_fc2)
{
    __shared__ float tile[64][68];
    int bid = blockIdx.x;
    const float* W; unsigned short* Wt; int K, N, tk, tn;
    if (bid < 108)      { W = qkv_w; Wt = o_qkv; K = 384;  N = 1152; tk = bid/18;        tn = bid%18; }
    else if (bid < 144) { W = proj_w; Wt = o_prj; K = 384;  N = 384;  tk = (bid-108)/6;  tn = (bid-108)%6; }
    else if (bid < 288) { W = fc1_w; Wt = o_fc1; K = 384;  N = 1536; tk = (bid-144)/24; tn = (bid-144)%24; }
    else                { W = fc2_w; Wt = o_fc2; K = 1536; N = 384;  tk = (bid-288)/6;  tn = (bid-288)%6; }
    int t = threadIdx.x;
    int lr = t >> 4, lc = (t & 15) * 4;
#pragma unroll
    for (int p = 0; p < 4; p++){
        float4 v = *(const float4*)(W + (size_t)(tk*64 + p*16 + lr) * N + tn*64 + lc);
        *(float4*)&tile[p*16 + lr][lc] = v;
    }
    __syncthreads();
    int n = t >> 2, k0 = (t & 3) * 16;
    unsigned int w[8];
#pragma unroll
    for (int i = 0; i < 8; i++)
        w[i] = (unsigned int)f2bf(tile[k0 + 2*i][n]) | ((unsigned int)f2bf(tile[k0 + 2*i + 1][n]) << 16);
    unsigned short* dst = Wt + (size_t)(tn*64 + n) * K + tk*64 + k0;
    *(uint4*)(dst)     = make_uint4(w[0], w[1], w[2], w[3]);
    *(uint4*)(dst + 8) = make_uint4(w[4], w[5], w[6], w[7]);
}

// ---------------- V transpose: vtmp [bh][ns][64] -> vb [bh][64][SEQ] ----------------
__global__ __launch_bounds__(256) void vt_kernel(const unsigned short* __restrict__ vtmp,
                                                 unsigned short* __restrict__ vb){
    __shared__ unsigned short tile[64][72];   // 144B row stride, 16B aligned
    int bh = blockIdx.y, ns0 = blockIdx.x * 64;
    const unsigned short* src = vtmp + ((size_t)bh * SEQ + ns0) * 64;
    int t = threadIdx.x;
#pragma unroll
    for (int p = 0; p < 2; p++){
        int idx = t + p * 256;
        int r = idx >> 3, c = (idx & 7) * 8;
        *(uint4*)&tile[r][c] = *(const uint4*)(src + (size_t)r * 64 + c);
    }
    __syncthreads();
    int d = t >> 2, j0 = (t & 3) * 16;
    unsigned int w[8];
#pragma unroll
    for (int m = 0; m < 8; m++)
        w[m] = (unsigned int)tile[j0 + 2*m][d] | ((unsigned int)tile[j0 + 2*m + 1][d] << 16);
    unsigned short* dst = vb + ((size_t)bh * 64 + d) * SEQ + ns0 + j0;
    *(uint4*)(dst)     = make_uint4(w[0], w[1], w[2], w[3]);
    *(uint4*)(dst + 8) = make_uint4(w[4], w[5], w[6], w[7]);
}

// ---------------- layernorm: x f32 [rows][384] -> bf16 out ----------------
__global__ __launch_bounds__(256) void ln_kernel(const float* __restrict__ x,
                                                 const float* __restrict__ g,
                                                 const float* __restrict__ b,
                                                 unsigned short* __restrict__ out){
    int row  = blockIdx.x * 4 + (threadIdx.x >> 6);
    int lane = threadIdx.x & 63;
    const float* xr = x + (size_t)row * DIM;
    float v[6];
#pragma unroll
    for (int p = 0; p < 3; p++){
        float2 t = *(const float2*)(xr + lane * 2 + p * 128);
        v[2*p] = t.x; v[2*p+1] = t.y;
    }
    float s = 0.f, sq = 0.f;
#pragma unroll
    for (int i = 0; i < 6; i++){ s += v[i]; sq += v[i] * v[i]; }
#pragma unroll
    for (int off = 1; off < 64; off <<= 1){
        s  += __shfl_xor(s, off);
        sq += __shfl_xor(sq, off);
    }
    float mu   = s * (1.0f / DIM);
    float var  = sq * (1.0f / DIM) - mu * mu;
    float rstd = rsqrtf(var + 1e-5f);
    unsigned short* orow = out + (size_t)row * DIM;
#pragma unroll
    for (int p = 0; p < 3; p++){
        int c = lane * 2 + p * 128;
        float h0 = (v[2*p]   - mu) * rstd * g[c]   + b[c];
        float h1 = (v[2*p+1] - mu) * rstd * g[c+1] + b[c+1];
        unsigned int pk = (unsigned int)f2bf(h0) | ((unsigned int)f2bf(h1) << 16);
        *(unsigned int*)(orow + c) = pk;
    }
}

// ---------------- GEMM: C[M][N] = A[M][K] * Wt[N][K]^T, fused epilogues ----------------
// BN=128: 4 waves in 2x2, 4x4 frags.  BN=64: 4 waves stacked, 2x4 frags (for skinny N).
// EPI 0: qkv scatter (q,k,v all [bh][ns][64] bf16, +bias)
// EPI 1: outf = resid + acc + bias (f32)
// EPI 2: outb = gelu(acc + bias) (bf16)
template<int EPI, int BN>
__global__ __launch_bounds__(256) void gemm_kernel(
    const unsigned short* __restrict__ A, const unsigned short* __restrict__ Bt,
    const float* __restrict__ bias, int K, int N,
    const float* __restrict__ resid, float* __restrict__ outf,
    unsigned short* __restrict__ outb,
    unsigned short* __restrict__ qb, unsigned short* __restrict__ kb2,
    unsigned short* __restrict__ vb)
{
    constexpr int FI = (BN == 128) ? 4 : 2;     // row frags per wave
    constexpr int WROWS = (BN == 128) ? 64 : 32;
    __shared__ __align__(16) unsigned short As[128 * 64];
    __shared__ __align__(16) unsigned short Bs[BN * 64];
    int t = threadIdx.x;
    int wid = t >> 6, lane = t & 63, quad = lane >> 4, l15 = lane & 15;
    int wr = (BN == 128) ? (wid >> 1) : wid;
    int wc = (BN == 128) ? (wid & 1) : 0;
    int row0 = blockIdx.y * 128, col0 = blockIdx.x * BN;
    int sr = lane >> 3, sc = lane & 7;
    int scl = (sc ^ sr) * 8;                    // global-side swizzled chunk

    const unsigned short* Ab = A  + (size_t)row0 * K;
    const unsigned short* Bb = Bt + (size_t)col0 * K;

    f32x4 acc[FI][4];
    f32x4 zz = {0.f, 0.f, 0.f, 0.f};
#pragma unroll
    for (int i = 0; i < FI; i++)
#pragma unroll
        for (int j = 0; j < 4; j++) acc[i][j] = zz;

    for (int k0 = 0; k0 < K; k0 += 64){
        __syncthreads();
#pragma unroll
        for (int j = 0; j < 4; j++){
            int rb = wid * 32 + j * 8;
            gload_lds16(Ab + (size_t)(rb + sr) * K + k0 + scl, &As[rb * 64]);
            if (BN == 128){
                gload_lds16(Bb + (size_t)(rb + sr) * K + k0 + scl, &Bs[rb * 64]);
            } else if (j < 2){
                int rb2 = wid * 16 + j * 8;
                gload_lds16(Bb + (size_t)(rb2 + sr) * K + k0 + scl, &Bs[rb2 * 64]);
            }
        }
        __syncthreads();
#pragma unroll
        for (int kk = 0; kk < 2; kk++){
            bf16x8 af[FI], bf[4];
#pragma unroll
            for (int i = 0; i < FI; i++){
                int r = wr*WROWS + i*16 + l15;
                af[i] = *(const bf16x8*)&As[r * 64 + (((kk*4 + quad) ^ (l15 & 7)) * 8)];
            }
#pragma unroll
            for (int j = 0; j < 4; j++){
                int r = wc*64 + j*16 + l15;
                bf[j] = *(const bf16x8*)&Bs[r * 64 + (((kk*4 + quad) ^ (l15 & 7)) * 8)];
            }
#pragma unroll
            for (int i = 0; i < FI; i++)
#pragma unroll
                for (int j = 0; j < 4; j++)
                    acc[i][j] = __builtin_amdgcn_mfma_f32_16x16x32_bf16(af[i], bf[j], acc[i][j], 0, 0, 0);
        }
    }

#pragma unroll
    for (int i = 0; i < FI; i++){
#pragma unroll
        for (int j = 0; j < 4; j++){
            int gr0 = row0 + wr*WROWS + i*16 + quad*4;
            int gc  = col0 + wc*64 + j*16 + l15;
            float bia = bias[gc];
#pragma unroll
            for (int r = 0; r < 4; r++){
                int gr = gr0 + r;
                float val = acc[i][j][r] + bia;
                if (EPI == 1){
                    outf[(size_t)gr * N + gc] = resid[(size_t)gr * N + gc] + val;
                } else if (EPI == 2){
                    // gelu(x) = x * e/(e+1), e = exp2(2*log2e*0.79788456*(x+0.044715x^3))
                    float u = val * (1.0f + 0.044715f * val * val);
                    float e = __builtin_amdgcn_exp2f(u * 2.3025851f); // 2*0.79788456*log2(e)
                    outb[(size_t)gr * N + gc] = f2bf(val * e / (e + 1.0f));
                } else {
                    int trip = gc / 384, rem = gc - trip * 384;
                    int head = rem >> 6, d = rem & 63;
                    int bidx = gr >> 11, ns = gr & 2047;
                    size_t off = ((size_t)(bidx * NHEAD + head) * SEQ + ns) * 64 + d;
                    unsigned short* dst = (trip == 0) ? qb : (trip == 1) ? kb2 : vb;
                    dst[off] = f2bf(val);
                }
            }
        }
    }
}

// ---------------- flash attention v3 ----------------
// 2 waves/block, 64 q-rows per wave (4 halves of 16). No-max softmax (exact:
// shift-invariant, scores are O(1)). K/V staged via global_load_lds. S^T = K*Q^T,
// P through per-wave LDS, O^T = V^T * P^T.
__global__ __launch_bounds__(128) void attn_kernel(const unsigned short* __restrict__ Q,
                                                   const unsigned short* __restrict__ Kb,
                                                   const unsigned short* __restrict__ Vt,
                                                   unsigned short* __restrict__ O){
    __shared__ __align__(16) unsigned short Ks[64 * 64];    // [kv][d], chunk-XOR swizzle
    __shared__ __align__(16) unsigned short Vs[64 * 64];    // [d][kv], same
    __shared__ __align__(16) unsigned short Ps[2][64 * 64]; // per-wave P [q][kv]

    int bh = blockIdx.y, qt = blockIdx.x;
    int t = threadIdx.x, wid = t >> 6, lane = t & 63, quad = lane >> 4, l15 = lane & 15;
    int l7 = l15 & 7;
    int q0 = qt * 128 + wid * 64;
    const unsigned short* Qp = Q  + (size_t)bh * SEQ * 64;
    const unsigned short* Kp = Kb + (size_t)bh * SEQ * 64;
    const unsigned short* Vp = Vt + (size_t)bh * 64 * SEQ;
    int sr = lane >> 3, sc = lane & 7;
    int scl = (sc ^ sr) * 8;

    const float QSCALE = 0.125f * 1.44269504f;  // fold 1/sqrt(64) and log2(e)
    bf16x8 qf[4][2];
#pragma unroll
    for (int h = 0; h < 4; h++){
#pragma unroll
        for (int c = 0; c < 2; c++){
            union { uint4 u; unsigned short s[8]; } cv;
            cv.u = *(const uint4*)(Qp + (size_t)(q0 + h*16 + l15) * 64 + c * 32 + quad * 8);
            bf16x8 f;
#pragma unroll
            for (int j = 0; j < 8; j++) f[j] = (short)f2bf(bf2f(cv.s[j]) * QSCALE);
            qf[h][c] = f;
        }
    }

    float li[4];
    f32x4 oacc[4][4];
    f32x4 zz = {0.f, 0.f, 0.f, 0.f};
#pragma unroll
    for (int h = 0; h < 4; h++){
        li[h] = 0.f;
#pragma unroll
        for (int dn = 0; dn < 4; dn++) oacc[h][dn] = zz;
    }
    unsigned short* P = &Ps[wid][0];

    for (int kt = 0; kt < SEQ / 64; kt++){
        __syncthreads();
#pragma unroll
        for (int jj = 0; jj < 4; jj++){
            int rb = wid * 32 + jj * 8;
            gload_lds16(Kp + (size_t)(kt*64 + rb + sr) * 64 + scl, &Ks[rb * 64]);
            gload_lds16(Vp + (size_t)(rb + sr) * SEQ + kt*64 + scl, &Vs[rb * 64]);
        }
        __syncthreads();

        // S^T: A = K-frag (rows kv), B = Q-frag; kf reused across 4 q-halves
        f32x4 st[4][4];
#pragma unroll
        for (int n = 0; n < 4; n++){
            int kv = n * 16 + l15;
            bf16x8 kf0 = *(const bf16x8*)(&Ks[kv * 64 + ((quad       ^ (kv & 7)) * 8)]);
            bf16x8 kf1 = *(const bf16x8*)(&Ks[kv * 64 + (((4 + quad) ^ (kv & 7)) * 8)]);
#pragma unroll
            for (int h = 0; h < 4; h++){
                f32x4 z = __builtin_amdgcn_mfma_f32_16x16x32_bf16(kf0, qf[h][0], zz, 0, 0, 0);
                st[h][n] = __builtin_amdgcn_mfma_f32_16x16x32_bf16(kf1, qf[h][1], z, 0, 0, 0);
            }
        }

        // no-max softmax: p = exp2(st) directly; row sum in-lane + 2 shuffles
#pragma unroll
        for (int h = 0; h < 4; h++){
            float rs = 0.f;
            int qloc = h * 16 + l15;
#pragma unroll
            for (int n = 0; n < 4; n++){
                float p0 = __builtin_amdgcn_exp2f(st[h][n][0]);
                float p1 = __builtin_amdgcn_exp2f(st[h][n][1]);
                float p2 = __builtin_amdgcn_exp2f(st[h][n][2]);
                float p3 = __builtin_amdgcn_exp2f(st[h][n][3]);
                rs += (p0 + p1) + (p2 + p3);
                unsigned int w0 = __builtin_amdgcn_perm(asu(p1) + 0x8000u, asu(p0) + 0x8000u, 0x07060302u);
                unsigned int w1 = __builtin_amdgcn_perm(asu(p3) + 0x8000u, asu(p2) + 0x8000u, 0x07060302u);
                int chunk = n * 2 + (quad >> 1);
                uint2* dst = (uint2*)(P + qloc * 64 + ((chunk ^ l7) * 8) + (quad & 1) * 4);
                *dst = make_uint2(w0, w1);
            }
            rs += __shfl_xor(rs, 16);
            rs += __shfl_xor(rs, 32);
            li[h] += rs;
        }

        asm volatile("s_waitcnt lgkmcnt(0)" ::: "memory");  // wave-private P w->r

        // O^T[d][q] += V^T * P^T; vf reused across 4 q-halves
#pragma unroll
        for (int c = 0; c < 2; c++){
            int chunk = c * 4 + quad;
            bf16x8 pf[4];
#pragma unroll
            for (int h = 0; h < 4; h++)
                pf[h] = *(const bf16x8*)(P + (h*16 + l15) * 64 + ((chunk ^ l7) * 8));
#pragma unroll
            for (int dn = 0; dn < 4; dn++){
                int d = dn * 16 + l15;
                bf16x8 vf = *(const bf16x8*)(&Vs[d * 64 + ((chunk ^ (d & 7)) * 8)]);
#pragma unroll
                for (int h = 0; h < 4; h++)
                    oacc[h][dn] = __builtin_amdgcn_mfma_f32_16x16x32_bf16(vf, pf[h], oacc[h][dn], 0, 0, 0);
            }
        }
    }

    int b = bh / NHEAD, hh = bh - b * NHEAD;
#pragma unroll
    for (int h = 0; h < 4; h++){
        float rd = 1.0f / li[h];
        size_t row = (size_t)(b * SEQ + q0 + h*16 + l15);
#pragma unroll
        for (int dn = 0; dn < 4; dn++){
            float v0 = oacc[h][dn][0] * rd, v1 = oacc[h][dn][1] * rd;
            float v2 = oacc[h][dn][2] * rd, v3 = oacc[h][dn][3] * rd;
            unsigned int w0 = (unsigned int)f2bf(v0) | ((unsigned int)f2bf(v1) << 16);
            unsigned int w1 = (unsigned int)f2bf(v2) | ((unsigned int)f2bf(v3) << 16);
            *(uint2*)(O + row * DIM + hh * 64 + dn * 16 + quad * 4) = make_uint2(w0, w1);
        }
    }
}

// ---------------- launcher ----------------
extern "C" void kernel_launch(void* const* d_in, const int* in_sizes, int n_in,
                              void* d_out, int out_size, void* d_ws, size_t ws_size,
                              hipStream_t stream){
    const float* x      = (const float*)d_in[0];
    const float* ln1_g  = (const float*)d_in[1];
    const float* ln1_b  = (const float*)d_in[2];
    const float* qkv_w  = (const float*)d_in[3];
    const float* qkv_b  = (const float*)d_in[4];
    const float* proj_w = (const float*)d_in[5];
    const float* proj_b = (const float*)d_in[6];
    const float* ln2_g  = (const float*)d_in[7];
    const float* ln2_b  = (const float*)d_in[8];
    const float* fc1_w  = (const float*)d_in[9];
    const float* fc1_b  = (const float*)d_in[10];
    const float* fc2_w  = (const float*)d_in[11];
    const float* fc2_b  = (const float*)d_in[12];
    float* out = (float*)d_out;

    char* p = (char*)d_ws;
    auto take = [&](size_t n){ char* r = p; p += (n + 255) & ~(size_t)255; return r; };
    unsigned short* wt_qkv = (unsigned short*)take((size_t)1152 * 384 * 2);
    unsigned short* wt_prj = (unsigned short*)take((size_t)384 * 384 * 2);
    unsigned short* wt_fc1 = (unsigned short*)take((size_t)1536 * 384 * 2);
    unsigned short* wt_fc2 = (unsigned short*)take((size_t)384 * 1536 * 2);
    unsigned short* rbig   = (unsigned short*)take((size_t)MTOT * 4 * DIM * 2); // h1|q|k|v, later hm
    unsigned short* h2     = (unsigned short*)take((size_t)MTOT * DIM * 2);     // vtmp, later ln2-out
    float*          x1     = (float*)take((size_t)MTOT * DIM * 4);

    unsigned short* h1     = rbig;
    unsigned short* qb     = rbig + (size_t)MTOT * DIM;
    unsigned short* kb     = qb   + (size_t)MTOT * DIM;
    unsigned short* vb     = kb   + (size_t)MTOT * DIM;
    unsigned short* vtmp   = h2;     // dead before ln2 writes h2
    unsigned short* attn_o = rbig;   // reuses h1 (dead after QKV gemm)
    unsigned short* hm     = rbig;   // reuses h1+qkv (dead after proj)

    wt_all_kernel<<<dim3(432), 256, 0, stream>>>(qkv_w, proj_w, fc1_w, fc2_w,
                                                 wt_qkv, wt_prj, wt_fc1, wt_fc2);
    ln_kernel<<<dim3(MTOT/4), 256, 0, stream>>>(x, ln1_g, ln1_b, h1);
    gemm_kernel<0,128><<<dim3(9, 128), 256, 0, stream>>>(h1, wt_qkv, qkv_b, 384, 1152,
                                                         nullptr, nullptr, nullptr, qb, kb, vtmp);
    vt_kernel<<<dim3(SEQ/64, BATCH*NHEAD), 256, 0, stream>>>(vtmp, vb);
    attn_kernel<<<dim3(SEQ/128, BATCH*NHEAD), 128, 0, stream>>>(qb, kb, vb, attn_o);
    gemm_kernel<1,64><<<dim3(6, 128), 256, 0, stream>>>(attn_o, wt_prj, proj_b, 384, 384,
                                                        x, x1, nullptr, nullptr, nullptr, nullptr);
    ln_kernel<<<dim3(MTOT/4), 256, 0, stream>>>(x1, ln2_g, ln2_b, h2);
    gemm_kernel<2,128><<<dim3(12, 128), 256, 0, stream>>>(h2, wt_fc1, fc1_b, 384, 1536,
                                                          nullptr, nullptr, hm, nullptr, nullptr, nullptr);
    gemm_kernel<1,64><<<dim3(6, 128), 256, 0, stream>>>(hm, wt_fc2, fc2_b, 1536, 384,
                                                        x1, out, nullptr, nullptr, nullptr, nullptr);
}

// Round 5
// 344.493 us; speedup vs baseline: 1.3097x; 1.0486x over previous
//
#include <hip/hip_runtime.h>
#include <hip/hip_bf16.h>

#define DIM   384
#define SEQ   2048
#define BATCH 8
#define NHEAD 6
#define HD    64
#define MLPD  1536
#define MTOT  (BATCH*SEQ)   // 16384 rows

typedef __attribute__((ext_vector_type(8))) short bf16x8;
typedef __attribute__((ext_vector_type(4))) float f32x4;

static __device__ __forceinline__ float bf2f(unsigned short u){
    union { float f; unsigned int i; } v; v.i = ((unsigned int)u) << 16; return v.f;
}
static __device__ __forceinline__ unsigned short f2bf(float f){
    union { float f; unsigned int i; } v; v.f = f;
    unsigned int r = v.i + 0x7fffu + ((v.i >> 16) & 1u);
    return (unsigned short)(r >> 16);
}
static __device__ __forceinline__ unsigned int asu(float f){
    union { float f; unsigned int i; } v; v.f = f; return v.i;
}
// async global->LDS, 16B per lane; LDS dst = wave-uniform base + lane*16
static __device__ __forceinline__ void gload_lds16(const unsigned short* g, unsigned short* l){
    __builtin_amdgcn_global_load_lds(
        (__attribute__((address_space(1))) void*)(g),
        (__attribute__((address_space(3))) void*)(l), 16, 0, 0);
}

// ---------------- merged weight transpose + cast, LDS-tiled ----------------
__global__ __launch_bounds__(256) void wt_all_kernel(
    const float* __restrict__ qkv_w, const float* __restrict__ proj_w,
    const float* __restrict__ fc1_w, const float* __restrict__ fc2_w,
    unsigned short* __restrict__ o_qkv, unsigned short* __restrict__ o_prj,
    unsigned short* __restrict__ o_fc1, unsigned short* __restrict__ o_fc2)
{
    __shared__ float tile[64][68];
    int bid = blockIdx.x;
    const float* W; unsigned short* Wt; int K, N, tk, tn;
    if (bid < 108)      { W = qkv_w; Wt = o_qkv; K = 384;  N = 1152; tk = bid/18;        tn = bid%18; }
    else if (bid < 144) { W = proj_w; Wt = o_prj; K = 384;  N = 384;  tk = (bid-108)/6;  tn = (bid-108)%6; }
    else if (bid < 288) { W = fc1_w; Wt = o_fc1; K = 384;  N = 1536; tk = (bid-144)/24; tn = (bid-144)%24; }
    else                { W = fc2_w; Wt = o_fc2; K = 1536; N = 384;  tk = (bid-288)/6;  tn = (bid-288)%6; }
    int t = threadIdx.x;
    int lr = t >> 4, lc = (t & 15) * 4;
#pragma unroll
    for (int p = 0; p < 4; p++){
        float4 v = *(const float4*)(W + (size_t)(tk*64 + p*16 + lr) * N + tn*64 + lc);
        *(float4*)&tile[p*16 + lr][lc] = v;
    }
    __syncthreads();
    int n = t >> 2, k0 = (t & 3) * 16;
    unsigned int w[8];
#pragma unroll
    for (int i = 0; i < 8; i++)
        w[i] = (unsigned int)f2bf(tile[k0 + 2*i][n]) | ((unsigned int)f2bf(tile[k0 + 2*i + 1][n]) << 16);
    unsigned short* dst = Wt + (size_t)(tn*64 + n) * K + tk*64 + k0;
    *(uint4*)(dst)     = make_uint4(w[0], w[1], w[2], w[3]);
    *(uint4*)(dst + 8) = make_uint4(w[4], w[5], w[6], w[7]);
}

// ---------------- V transpose: vtmp [bh][ns][64] -> vb [bh][64][SEQ] ----------------
__global__ __launch_bounds__(256) void vt_kernel(const unsigned short* __restrict__ vtmp,
                                                 unsigned short* __restrict__ vb){
    __shared__ unsigned short tile[64][72];
    int bh = blockIdx.y, ns0 = blockIdx.x * 64;
    const unsigned short* src = vtmp + ((size_t)bh * SEQ + ns0) * 64;
    int t = threadIdx.x;
#pragma unroll
    for (int p = 0; p < 2; p++){
        int idx = t + p * 256;
        int r = idx >> 3, c = (idx & 7) * 8;
        *(uint4*)&tile[r][c] = *(const uint4*)(src + (size_t)r * 64 + c);
    }
    __syncthreads();
    int d = t >> 2, j0 = (t & 3) * 16;
    unsigned int w[8];
#pragma unroll
    for (int m = 0; m < 8; m++)
        w[m] = (unsigned int)tile[j0 + 2*m][d] | ((unsigned int)tile[j0 + 2*m + 1][d] << 16);
    unsigned short* dst = vb + ((size_t)bh * 64 + d) * SEQ + ns0 + j0;
    *(uint4*)(dst)     = make_uint4(w[0], w[1], w[2], w[3]);
    *(uint4*)(dst + 8) = make_uint4(w[4], w[5], w[6], w[7]);
}

// ---------------- layernorm: x f32 [rows][384] -> bf16 out ----------------
__global__ __launch_bounds__(256) void ln_kernel(const float* __restrict__ x,
                                                 const float* __restrict__ g,
                                                 const float* __restrict__ b,
                                                 unsigned short* __restrict__ out){
    int row  = blockIdx.x * 4 + (threadIdx.x >> 6);
    int lane = threadIdx.x & 63;
    const float* xr = x + (size_t)row * DIM;
    float v[6];
#pragma unroll
    for (int p = 0; p < 3; p++){
        float2 t = *(const float2*)(xr + lane * 2 + p * 128);
        v[2*p] = t.x; v[2*p+1] = t.y;
    }
    float s = 0.f, sq = 0.f;
#pragma unroll
    for (int i = 0; i < 6; i++){ s += v[i]; sq += v[i] * v[i]; }
#pragma unroll
    for (int off = 1; off < 64; off <<= 1){
        s  += __shfl_xor(s, off);
        sq += __shfl_xor(sq, off);
    }
    float mu   = s * (1.0f / DIM);
    float var  = sq * (1.0f / DIM) - mu * mu;
    float rstd = rsqrtf(var + 1e-5f);
    unsigned short* orow = out + (size_t)row * DIM;
#pragma unroll
    for (int p = 0; p < 3; p++){
        int c = lane * 2 + p * 128;
        float h0 = (v[2*p]   - mu) * rstd * g[c]   + b[c];
        float h1 = (v[2*p+1] - mu) * rstd * g[c+1] + b[c+1];
        unsigned int pk = (unsigned int)f2bf(h0) | ((unsigned int)f2bf(h1) << 16);
        *(unsigned int*)(orow + c) = pk;
    }
}

// ---------------- GEMM: C[M][N] = A[M][K] * Wt[N][K]^T, fused epilogues ----------------
template<int EPI, int BN>
__global__ __launch_bounds__(256) void gemm_kernel(
    const unsigned short* __restrict__ A, const unsigned short* __restrict__ Bt,
    const float* __restrict__ bias, int K, int N,
    const float* __restrict__ resid, float* __restrict__ outf,
    unsigned short* __restrict__ outb,
    unsigned short* __restrict__ qb, unsigned short* __restrict__ kb2,
    unsigned short* __restrict__ vb)
{
    constexpr int FI = (BN == 128) ? 4 : 2;
    constexpr int WROWS = (BN == 128) ? 64 : 32;
    __shared__ __align__(16) unsigned short As[128 * 64];
    __shared__ __align__(16) unsigned short Bs[BN * 64];
    int t = threadIdx.x;
    int wid = t >> 6, lane = t & 63, quad = lane >> 4, l15 = lane & 15;
    int wr = (BN == 128) ? (wid >> 1) : wid;
    int wc = (BN == 128) ? (wid & 1) : 0;
    int row0 = blockIdx.y * 128, col0 = blockIdx.x * BN;
    int sr = lane >> 3, sc = lane & 7;
    int scl = (sc ^ sr) * 8;

    const unsigned short* Ab = A  + (size_t)row0 * K;
    const unsigned short* Bb = Bt + (size_t)col0 * K;

    f32x4 acc[FI][4];
    f32x4 zz = {0.f, 0.f, 0.f, 0.f};
#pragma unroll
    for (int i = 0; i < FI; i++)
#pragma unroll
        for (int j = 0; j < 4; j++) acc[i][j] = zz;

    for (int k0 = 0; k0 < K; k0 += 64){
        __syncthreads();
#pragma unroll
        for (int j = 0; j < 4; j++){
            int rb = wid * 32 + j * 8;
            gload_lds16(Ab + (size_t)(rb + sr) * K + k0 + scl, &As[rb * 64]);
            if (BN == 128){
                gload_lds16(Bb + (size_t)(rb + sr) * K + k0 + scl, &Bs[rb * 64]);
            } else if (j < 2){
                int rb2 = wid * 16 + j * 8;
                gload_lds16(Bb + (size_t)(rb2 + sr) * K + k0 + scl, &Bs[rb2 * 64]);
            }
        }
        __syncthreads();
#pragma unroll
        for (int kk = 0; kk < 2; kk++){
            bf16x8 af[FI], bf[4];
#pragma unroll
            for (int i = 0; i < FI; i++){
                int r = wr*WROWS + i*16 + l15;
                af[i] = *(const bf16x8*)&As[r * 64 + (((kk*4 + quad) ^ (l15 & 7)) * 8)];
            }
#pragma unroll
            for (int j = 0; j < 4; j++){
                int r = wc*64 + j*16 + l15;
                bf[j] = *(const bf16x8*)&Bs[r * 64 + (((kk*4 + quad) ^ (l15 & 7)) * 8)];
            }
#pragma unroll
            for (int i = 0; i < FI; i++)
#pragma unroll
                for (int j = 0; j < 4; j++)
                    acc[i][j] = __builtin_amdgcn_mfma_f32_16x16x32_bf16(af[i], bf[j], acc[i][j], 0, 0, 0);
        }
    }

#pragma unroll
    for (int i = 0; i < FI; i++){
#pragma unroll
        for (int j = 0; j < 4; j++){
            int gr0 = row0 + wr*WROWS + i*16 + quad*4;
            int gc  = col0 + wc*64 + j*16 + l15;
            float bia = bias[gc];
#pragma unroll
            for (int r = 0; r < 4; r++){
                int gr = gr0 + r;
                float val = acc[i][j][r] + bia;
                if (EPI == 1){
                    outf[(size_t)gr * N + gc] = resid[(size_t)gr * N + gc] + val;
                } else if (EPI == 2){
                    float u = val * (1.0f + 0.044715f * val * val);
                    float e = __builtin_amdgcn_exp2f(u * 2.3025851f);
                    outb[(size_t)gr * N + gc] = f2bf(val * e / (e + 1.0f));
                } else {
                    int trip = gc / 384, rem = gc - trip * 384;
                    int head = rem >> 6, d = rem & 63;
                    int bidx = gr >> 11, ns = gr & 2047;
                    size_t off = ((size_t)(bidx * NHEAD + head) * SEQ + ns) * 64 + d;
                    unsigned short* dst = (trip == 0) ? qb : (trip == 1) ? kb2 : vb;
                    dst[off] = f2bf(val);
                }
            }
        }
    }
}

// ---------------- flash attention v4 ----------------
// 2 waves/block, 32 q-rows/wave (q-tile 64), grid (32, 48) = 1536 blocks
// -> 6 blocks/CU, 12 waves/CU (TLP to hide DS/MFMA latency).
// No-max softmax (exact: shift-invariant, scores O(1)); global_load_lds staging;
// S^T = K*Q^T; P via per-wave LDS; O^T = V^T*P^T.  LDS = 8+8+8 = 24 KB.
__global__ __launch_bounds__(128) void attn_kernel(const unsigned short* __restrict__ Q,
                                                   const unsigned short* __restrict__ Kb,
                                                   const unsigned short* __restrict__ Vt,
                                                   unsigned short* __restrict__ O){
    __shared__ __align__(16) unsigned short Ks[64 * 64];    // [kv][d], chunk-XOR swizzle
    __shared__ __align__(16) unsigned short Vs[64 * 64];    // [d][kv], same
    __shared__ __align__(16) unsigned short Ps[2][32 * 64]; // per-wave P [q][kv]

    int bh = blockIdx.y, qt = blockIdx.x;
    int t = threadIdx.x, wid = t >> 6, lane = t & 63, quad = lane >> 4, l15 = lane & 15;
    int l7 = l15 & 7;
    int q0 = qt * 64 + wid * 32;
    const unsigned short* Qp = Q  + (size_t)bh * SEQ * 64;
    const unsigned short* Kp = Kb + (size_t)bh * SEQ * 64;
    const unsigned short* Vp = Vt + (size_t)bh * 64 * SEQ;
    int sr = lane >> 3, sc = lane & 7;
    int scl = (sc ^ sr) * 8;

    const float QSCALE = 0.125f * 1.44269504f;  // fold 1/sqrt(64) and log2(e)
    bf16x8 qf[2][2];
#pragma unroll
    for (int h = 0; h < 2; h++){
#pragma unroll
        for (int c = 0; c < 2; c++){
            union { uint4 u; unsigned short s[8]; } cv;
            cv.u = *(const uint4*)(Qp + (size_t)(q0 + h*16 + l15) * 64 + c * 32 + quad * 8);
            bf16x8 f;
#pragma unroll
            for (int j = 0; j < 8; j++) f[j] = (short)f2bf(bf2f(cv.s[j]) * QSCALE);
            qf[h][c] = f;
        }
    }

    float li[2];
    f32x4 oacc[2][4];
    f32x4 zz = {0.f, 0.f, 0.f, 0.f};
#pragma unroll
    for (int h = 0; h < 2; h++){
        li[h] = 0.f;
#pragma unroll
        for (int dn = 0; dn < 4; dn++) oacc[h][dn] = zz;
    }
    unsigned short* P = &Ps[wid][0];

    for (int kt = 0; kt < SEQ / 64; kt++){
        __syncthreads();
#pragma unroll
        for (int jj = 0; jj < 4; jj++){
            int rb = wid * 32 + jj * 8;
            gload_lds16(Kp + (size_t)(kt*64 + rb + sr) * 64 + scl, &Ks[rb * 64]);
            gload_lds16(Vp + (size_t)(rb + sr) * SEQ + kt*64 + scl, &Vs[rb * 64]);
        }
        __syncthreads();

        // S^T: A = K-frag (rows kv), B = Q-frag; kf reused across 2 q-halves
        f32x4 st[2][4];
#pragma unroll
        for (int n = 0; n < 4; n++){
            int kv = n * 16 + l15;
            bf16x8 kf0 = *(const bf16x8*)(&Ks[kv * 64 + ((quad       ^ (kv & 7)) * 8)]);
            bf16x8 kf1 = *(const bf16x8*)(&Ks[kv * 64 + (((4 + quad) ^ (kv & 7)) * 8)]);
#pragma unroll
            for (int h = 0; h < 2; h++){
                f32x4 z = __builtin_amdgcn_mfma_f32_16x16x32_bf16(kf0, qf[h][0], zz, 0, 0, 0);
                st[h][n] = __builtin_amdgcn_mfma_f32_16x16x32_bf16(kf1, qf[h][1], z, 0, 0, 0);
            }
        }

        // no-max softmax: p = exp2(st); row sum in-lane + 2 shuffles
#pragma unroll
        for (int h = 0; h < 2; h++){
            float rs = 0.f;
            int qloc = h * 16 + l15;
#pragma unroll
            for (int n = 0; n < 4; n++){
                float p0 = __builtin_amdgcn_exp2f(st[h][n][0]);
                float p1 = __builtin_amdgcn_exp2f(st[h][n][1]);
                float p2 = __builtin_amdgcn_exp2f(st[h][n][2]);
                float p3 = __builtin_amdgcn_exp2f(st[h][n][3]);
                rs += (p0 + p1) + (p2 + p3);
                unsigned int w0 = __builtin_amdgcn_perm(asu(p1) + 0x8000u, asu(p0) + 0x8000u, 0x07060302u);
                unsigned int w1 = __builtin_amdgcn_perm(asu(p3) + 0x8000u, asu(p2) + 0x8000u, 0x07060302u);
                int chunk = n * 2 + (quad >> 1);
                uint2* dst = (uint2*)(P + qloc * 64 + ((chunk ^ l7) * 8) + (quad & 1) * 4);
                *dst = make_uint2(w0, w1);
            }
            rs += __shfl_xor(rs, 16);
            rs += __shfl_xor(rs, 32);
            li[h] += rs;
        }

        asm volatile("s_waitcnt lgkmcnt(0)" ::: "memory");  // wave-private P w->r

        // O^T[d][q] += V^T * P^T; vf reused across 2 q-halves
#pragma unroll
        for (int c = 0; c < 2; c++){
            int chunk = c * 4 + quad;
            bf16x8 pf[2];
#pragma unroll
            for (int h = 0; h < 2; h++)
                pf[h] = *(const bf16x8*)(P + (h*16 + l15) * 64 + ((chunk ^ l7) * 8));
#pragma unroll
            for (int dn = 0; dn < 4; dn++){
                int d = dn * 16 + l15;
                bf16x8 vf = *(const bf16x8*)(&Vs[d * 64 + ((chunk ^ (d & 7)) * 8)]);
#pragma unroll
                for (int h = 0; h < 2; h++)
                    oacc[h][dn] = __builtin_amdgcn_mfma_f32_16x16x32_bf16(vf, pf[h], oacc[h][dn], 0, 0, 0);
            }
        }
    }

    int b = bh / NHEAD, hh = bh - b * NHEAD;
#pragma unroll
    for (int h = 0; h < 2; h++){
        float rd = 1.0f / li[h];
        size_t row = (size_t)(b * SEQ + q0 + h*16 + l15);
#pragma unroll
        for (int dn = 0; dn < 4; dn++){
            float v0 = oacc[h][dn][0] * rd, v1 = oacc[h][dn][1] * rd;
            float v2 = oacc[h][dn][2] * rd, v3 = oacc[h][dn][3] * rd;
            unsigned int w0 = (unsigned int)f2bf(v0) | ((unsigned int)f2bf(v1) << 16);
            unsigned int w1 = (unsigned int)f2bf(v2) | ((unsigned int)f2bf(v3) << 16);
            *(uint2*)(O + row * DIM + hh * 64 + dn * 16 + quad * 4) = make_uint2(w0, w1);
        }
    }
}

// ---------------- launcher ----------------
extern "C" void kernel_launch(void* const* d_in, const int* in_sizes, int n_in,
                              void* d_out, int out_size, void* d_ws, size_t ws_size,
                              hipStream_t stream){
    const float* x      = (const float*)d_in[0];
    const float* ln1_g  = (const float*)d_in[1];
    const float* ln1_b  = (const float*)d_in[2];
    const float* qkv_w  = (const float*)d_in[3];
    const float* qkv_b  = (const float*)d_in[4];
    const float* proj_w = (const float*)d_in[5];
    const float* proj_b = (const float*)d_in[6];
    const float* ln2_g  = (const float*)d_in[7];
    const float* ln2_b  = (const float*)d_in[8];
    const float* fc1_w  = (const float*)d_in[9];
    const float* fc1_b  = (const float*)d_in[10];
    const float* fc2_w  = (const float*)d_in[11];
    const float* fc2_b  = (const float*)d_in[12];
    float* out = (float*)d_out;

    char* p = (char*)d_ws;
    auto take = [&](size_t n){ char* r = p; p += (n + 255) & ~(size_t)255; return r; };
    unsigned short* wt_qkv = (unsigned short*)take((size_t)1152 * 384 * 2);
    unsigned short* wt_prj = (unsigned short*)take((size_t)384 * 384 * 2);
    unsigned short* wt_fc1 = (unsigned short*)take((size_t)1536 * 384 * 2);
    unsigned short* wt_fc2 = (unsigned short*)take((size_t)384 * 1536 * 2);
    unsigned short* rbig   = (unsigned short*)take((size_t)MTOT * 4 * DIM * 2); // h1|q|k|v, later hm
    unsigned short* h2     = (unsigned short*)take((size_t)MTOT * DIM * 2);     // vtmp, later ln2-out
    float*          x1     = (float*)take((size_t)MTOT * DIM * 4);

    unsigned short* h1     = rbig;
    unsigned short* qb     = rbig + (size_t)MTOT * DIM;
    unsigned short* kb     = qb   + (size_t)MTOT * DIM;
    unsigned short* vb     = kb   + (size_t)MTOT * DIM;
    unsigned short* vtmp   = h2;     // dead before ln2 writes h2
    unsigned short* attn_o = rbig;   // reuses h1 (dead after QKV gemm)
    unsigned short* hm     = rbig;   // reuses h1+qkv (dead after proj)

    wt_all_kernel<<<dim3(432), 256, 0, stream>>>(qkv_w, proj_w, fc1_w, fc2_w,
                                                 wt_qkv, wt_prj, wt_fc1, wt_fc2);
    ln_kernel<<<dim3(MTOT/4), 256, 0, stream>>>(x, ln1_g, ln1_b, h1);
    gemm_kernel<0,128><<<dim3(9, 128), 256, 0, stream>>>(h1, wt_qkv, qkv_b, 384, 1152,
                                                         nullptr, nullptr, nullptr, qb, kb, vtmp);
    vt_kernel<<<dim3(SEQ/64, BATCH*NHEAD), 256, 0, stream>>>(vtmp, vb);
    attn_kernel<<<dim3(SEQ/64, BATCH*NHEAD), 128, 0, stream>>>(qb, kb, vb, attn_o);
    gemm_kernel<1,64><<<dim3(6, 128), 256, 0, stream>>>(attn_o, wt_prj, proj_b, 384, 384,
                                                        x, x1, nullptr, nullptr, nullptr, nullptr);
    ln_kernel<<<dim3(MTOT/4), 256, 0, stream>>>(x1, ln2_g, ln2_b, h2);
    gemm_kernel<2,128><<<dim3(12, 128), 256, 0, stream>>>(h2, wt_fc1, fc1_b, 384, 1536,
                                                          nullptr, nullptr, hm, nullptr, nullptr, nullptr);
    gemm_kernel<1,64><<<dim3(6, 128), 256, 0, stream>>>(hm, wt_fc2, fc2_b, 1536, 384,
                                                        x1, out, nullptr, nullptr, nullptr, nullptr);
}

// Round 6
// 329.505 us; speedup vs baseline: 1.3693x; 1.0455x over previous
//
#include <hip/hip_runtime.h>
#include <hip/hip_bf16.h>

#define DIM   384
#define SEQ   2048
#define BATCH 8
#define NHEAD 6
#define HD    64
#define MLPD  1536
#define MTOT  (BATCH*SEQ)   // 16384 rows

typedef __attribute__((ext_vector_type(8))) short bf16x8;
typedef __attribute__((ext_vector_type(4))) float f32x4;

static __device__ __forceinline__ float bf2f(unsigned short u){
    union { float f; unsigned int i; } v; v.i = ((unsigned int)u) << 16; return v.f;
}
static __device__ __forceinline__ unsigned short f2bf(float f){
    union { float f; unsigned int i; } v; v.f = f;
    unsigned int r = v.i + 0x7fffu + ((v.i >> 16) & 1u);
    return (unsigned short)(r >> 16);
}
static __device__ __forceinline__ unsigned int asu(float f){
    union { float f; unsigned int i; } v; v.f = f; return v.i;
}
// async global->LDS, 16B per lane; LDS dst = wave-uniform base + lane*16
static __device__ __forceinline__ void gload_lds16(const unsigned short* g, unsigned short* l){
    __builtin_amdgcn_global_load_lds(
        (__attribute__((address_space(1))) void*)(g),
        (__attribute__((address_space(3))) void*)(l), 16, 0, 0);
}

// ---------------- merged weight transpose + cast, LDS-tiled ----------------
__global__ __launch_bounds__(256) void wt_all_kernel(
    const float* __restrict__ qkv_w, const float* __restrict__ proj_w,
    const float* __restrict__ fc1_w, const float* __restrict__ fc2_w,
    unsigned short* __restrict__ o_qkv, unsigned short* __restrict__ o_prj,
    unsigned short* __restrict__ o_fc1, unsigned short* __restrict__ o_fc2)
{
    __shared__ float tile[64][68];
    int bid = blockIdx.x;
    const float* W; unsigned short* Wt; int K, N, tk, tn;
    if (bid < 108)      { W = qkv_w; Wt = o_qkv; K = 384;  N = 1152; tk = bid/18;        tn = bid%18; }
    else if (bid < 144) { W = proj_w; Wt = o_prj; K = 384;  N = 384;  tk = (bid-108)/6;  tn = (bid-108)%6; }
    else if (bid < 288) { W = fc1_w; Wt = o_fc1; K = 384;  N = 1536; tk = (bid-144)/24; tn = (bid-144)%24; }
    else                { W = fc2_w; Wt = o_fc2; K = 1536; N = 384;  tk = (bid-288)/6;  tn = (bid-288)%6; }
    int t = threadIdx.x;
    int lr = t >> 4, lc = (t & 15) * 4;
#pragma unroll
    for (int p = 0; p < 4; p++){
        float4 v = *(const float4*)(W + (size_t)(tk*64 + p*16 + lr) * N + tn*64 + lc);
        *(float4*)&tile[p*16 + lr][lc] = v;
    }
    __syncthreads();
    int n = t >> 2, k0 = (t & 3) * 16;
    unsigned int w[8];
#pragma unroll
    for (int i = 0; i < 8; i++)
        w[i] = (unsigned int)f2bf(tile[k0 + 2*i][n]) | ((unsigned int)f2bf(tile[k0 + 2*i + 1][n]) << 16);
    unsigned short* dst = Wt + (size_t)(tn*64 + n) * K + tk*64 + k0;
    *(uint4*)(dst)     = make_uint4(w[0], w[1], w[2], w[3]);
    *(uint4*)(dst + 8) = make_uint4(w[4], w[5], w[6], w[7]);
}

// ---------------- V transpose: vtmp [bh][ns][64] -> vb [bh][64][SEQ] ----------------
__global__ __launch_bounds__(256) void vt_kernel(const unsigned short* __restrict__ vtmp,
                                                 unsigned short* __restrict__ vb){
    __shared__ unsigned short tile[64][72];
    int bh = blockIdx.y, ns0 = blockIdx.x * 64;
    const unsigned short* src = vtmp + ((size_t)bh * SEQ + ns0) * 64;
    int t = threadIdx.x;
#pragma unroll
    for (int p = 0; p < 2; p++){
        int idx = t + p * 256;
        int r = idx >> 3, c = (idx & 7) * 8;
        *(uint4*)&tile[r][c] = *(const uint4*)(src + (size_t)r * 64 + c);
    }
    __syncthreads();
    int d = t >> 2, j0 = (t & 3) * 16;
    unsigned int w[8];
#pragma unroll
    for (int m = 0; m < 8; m++)
        w[m] = (unsigned int)tile[j0 + 2*m][d] | ((unsigned int)tile[j0 + 2*m + 1][d] << 16);
    unsigned short* dst = vb + ((size_t)bh * 64 + d) * SEQ + ns0 + j0;
    *(uint4*)(dst)     = make_uint4(w[0], w[1], w[2], w[3]);
    *(uint4*)(dst + 8) = make_uint4(w[4], w[5], w[6], w[7]);
}

// ---------------- layernorm: x f32 [rows][384] -> bf16 out ----------------
__global__ __launch_bounds__(256) void ln_kernel(const float* __restrict__ x,
                                                 const float* __restrict__ g,
                                                 const float* __restrict__ b,
                                                 unsigned short* __restrict__ out){
    int row  = blockIdx.x * 4 + (threadIdx.x >> 6);
    int lane = threadIdx.x & 63;
    const float* xr = x + (size_t)row * DIM;
    float v[6];
#pragma unroll
    for (int p = 0; p < 3; p++){
        float2 t = *(const float2*)(xr + lane * 2 + p * 128);
        v[2*p] = t.x; v[2*p+1] = t.y;
    }
    float s = 0.f, sq = 0.f;
#pragma unroll
    for (int i = 0; i < 6; i++){ s += v[i]; sq += v[i] * v[i]; }
#pragma unroll
    for (int off = 1; off < 64; off <<= 1){
        s  += __shfl_xor(s, off);
        sq += __shfl_xor(sq, off);
    }
    float mu   = s * (1.0f / DIM);
    float var  = sq * (1.0f / DIM) - mu * mu;
    float rstd = rsqrtf(var + 1e-5f);
    unsigned short* orow = out + (size_t)row * DIM;
#pragma unroll
    for (int p = 0; p < 3; p++){
        int c = lane * 2 + p * 128;
        float h0 = (v[2*p]   - mu) * rstd * g[c]   + b[c];
        float h1 = (v[2*p+1] - mu) * rstd * g[c+1] + b[c+1];
        unsigned int pk = (unsigned int)f2bf(h0) | ((unsigned int)f2bf(h1) << 16);
        *(unsigned int*)(orow + c) = pk;
    }
}

// ---------------- GEMM: C[M][N] = A[M][K] * Wt[N][K]^T, fused epilogues ----------------
template<int EPI, int BN>
__global__ __launch_bounds__(256) void gemm_kernel(
    const unsigned short* __restrict__ A, const unsigned short* __restrict__ Bt,
    const float* __restrict__ bias, int K, int N,
    const float* __restrict__ resid, float* __restrict__ outf,
    unsigned short* __restrict__ outb,
    unsigned short* __restrict__ qb, unsigned short* __restrict__ kb2,
    unsigned short* __restrict__ vb)
{
    constexpr int FI = (BN == 128) ? 4 : 2;
    constexpr int WROWS = (BN == 128) ? 64 : 32;
    __shared__ __align__(16) unsigned short As[128 * 64];
    __shared__ __align__(16) unsigned short Bs[BN * 64];
    int t = threadIdx.x;
    int wid = t >> 6, lane = t & 63, quad = lane >> 4, l15 = lane & 15;
    int wr = (BN == 128) ? (wid >> 1) : wid;
    int wc = (BN == 128) ? (wid & 1) : 0;
    int row0 = blockIdx.y * 128, col0 = blockIdx.x * BN;
    int sr = lane >> 3, sc = lane & 7;
    int scl = (sc ^ sr) * 8;

    const unsigned short* Ab = A  + (size_t)row0 * K;
    const unsigned short* Bb = Bt + (size_t)col0 * K;

    f32x4 acc[FI][4];
    f32x4 zz = {0.f, 0.f, 0.f, 0.f};
#pragma unroll
    for (int i = 0; i < FI; i++)
#pragma unroll
        for (int j = 0; j < 4; j++) acc[i][j] = zz;

    for (int k0 = 0; k0 < K; k0 += 64){
        __syncthreads();
#pragma unroll
        for (int j = 0; j < 4; j++){
            int rb = wid * 32 + j * 8;
            gload_lds16(Ab + (size_t)(rb + sr) * K + k0 + scl, &As[rb * 64]);
            if (BN == 128){
                gload_lds16(Bb + (size_t)(rb + sr) * K + k0 + scl, &Bs[rb * 64]);
            } else if (j < 2){
                int rb2 = wid * 16 + j * 8;
                gload_lds16(Bb + (size_t)(rb2 + sr) * K + k0 + scl, &Bs[rb2 * 64]);
            }
        }
        __syncthreads();
#pragma unroll
        for (int kk = 0; kk < 2; kk++){
            bf16x8 af[FI], bf[4];
#pragma unroll
            for (int i = 0; i < FI; i++){
                int r = wr*WROWS + i*16 + l15;
                af[i] = *(const bf16x8*)&As[r * 64 + (((kk*4 + quad) ^ (l15 & 7)) * 8)];
            }
#pragma unroll
            for (int j = 0; j < 4; j++){
                int r = wc*64 + j*16 + l15;
                bf[j] = *(const bf16x8*)&Bs[r * 64 + (((kk*4 + quad) ^ (l15 & 7)) * 8)];
            }
#pragma unroll
            for (int i = 0; i < FI; i++)
#pragma unroll
                for (int j = 0; j < 4; j++)
                    acc[i][j] = __builtin_amdgcn_mfma_f32_16x16x32_bf16(af[i], bf[j], acc[i][j], 0, 0, 0);
        }
    }

#pragma unroll
    for (int i = 0; i < FI; i++){
#pragma unroll
        for (int j = 0; j < 4; j++){
            int gr0 = row0 + wr*WROWS + i*16 + quad*4;
            int gc  = col0 + wc*64 + j*16 + l15;
            float bia = bias[gc];
#pragma unroll
            for (int r = 0; r < 4; r++){
                int gr = gr0 + r;
                float val = acc[i][j][r] + bia;
                if (EPI == 1){
                    outf[(size_t)gr * N + gc] = resid[(size_t)gr * N + gc] + val;
                } else if (EPI == 2){
                    float u = val * (1.0f + 0.044715f * val * val);
                    float e = __builtin_amdgcn_exp2f(u * 2.3025851f);
                    outb[(size_t)gr * N + gc] = f2bf(val * e / (e + 1.0f));
                } else {
                    int trip = gc / 384, rem = gc - trip * 384;
                    int head = rem >> 6, d = rem & 63;
                    int bidx = gr >> 11, ns = gr & 2047;
                    size_t off = ((size_t)(bidx * NHEAD + head) * SEQ + ns) * 64 + d;
                    unsigned short* dst = (trip == 0) ? qb : (trip == 1) ? kb2 : vb;
                    dst[off] = f2bf(val);
                }
            }
        }
    }
}

// ---------------- flash attention v5 ----------------
// 2 waves/block, 32 q-rows/wave, grid (32,48)=1536 blocks (6/CU, 12 waves/CU).
// VALU-minimal softmax: no-max (exact, shift-invariant), truncating bf16 pack,
// row-sum li via ones-MFMA, ALL LDS addresses hoisted out of the kt loop.
__global__ __launch_bounds__(128, 3) void attn_kernel(const unsigned short* __restrict__ Q,
                                                      const unsigned short* __restrict__ Kb,
                                                      const unsigned short* __restrict__ Vt,
                                                      unsigned short* __restrict__ O){
    __shared__ __align__(16) unsigned short Ks[64 * 64];    // [kv][d], chunk-XOR swizzle
    __shared__ __align__(16) unsigned short Vs[64 * 64];    // [d][kv], same
    __shared__ __align__(16) unsigned short Ps[2][32 * 64]; // per-wave P [q][kv]

    int bh = blockIdx.y, qt = blockIdx.x;
    int t = threadIdx.x, wid = t >> 6, lane = t & 63, quad = lane >> 4, l15 = lane & 15;
    int l7 = l15 & 7;
    int q0 = qt * 64 + wid * 32;
    const unsigned short* Qp = Q  + (size_t)bh * SEQ * 64;
    const unsigned short* Kp = Kb + (size_t)bh * SEQ * 64;
    const unsigned short* Vp = Vt + (size_t)bh * 64 * SEQ;
    int sr = lane >> 3, sc = lane & 7;
    int scl = (sc ^ sr) * 8;

    const float QSCALE = 0.125f * 1.44269504f;  // fold 1/sqrt(64) and log2(e)
    bf16x8 qf[2][2];
#pragma unroll
    for (int h = 0; h < 2; h++){
#pragma unroll
        for (int c = 0; c < 2; c++){
            union { uint4 u; unsigned short s[8]; } cv;
            cv.u = *(const uint4*)(Qp + (size_t)(q0 + h*16 + l15) * 64 + c * 32 + quad * 8);
            bf16x8 f;
#pragma unroll
            for (int j = 0; j < 8; j++) f[j] = (short)f2bf(bf2f(cv.s[j]) * QSCALE);
            qf[h][c] = f;
        }
    }

    bf16x8 ones;
#pragma unroll
    for (int j = 0; j < 8; j++) ones[j] = (short)0x3F80;    // bf16 1.0

    f32x4 oacc[2][4], sacc[2];
    f32x4 zz = {0.f, 0.f, 0.f, 0.f};
#pragma unroll
    for (int h = 0; h < 2; h++){
        sacc[h] = zz;
#pragma unroll
        for (int dn = 0; dn < 4; dn++) oacc[h][dn] = zz;
    }
    unsigned short* P = &Ps[wid][0];

    // ---- hoisted LDS addresses (kt-invariant) ----
    const unsigned short* kf_ptr[4][2];
#pragma unroll
    for (int n = 0; n < 4; n++){
        int kv = n * 16 + l15;
        kf_ptr[n][0] = &Ks[kv * 64 + ((quad       ^ (kv & 7)) * 8)];
        kf_ptr[n][1] = &Ks[kv * 64 + (((4 + quad) ^ (kv & 7)) * 8)];
    }
    const unsigned short* vf_ptr[2][4];
#pragma unroll
    for (int c = 0; c < 2; c++)
#pragma unroll
        for (int dn = 0; dn < 4; dn++){
            int d = dn * 16 + l15;
            vf_ptr[c][dn] = &Vs[d * 64 + (((c*4 + quad) ^ (d & 7)) * 8)];
        }
    const unsigned short* pf_ptr[2][2];
#pragma unroll
    for (int c = 0; c < 2; c++)
#pragma unroll
        for (int h = 0; h < 2; h++)
            pf_ptr[c][h] = P + (h*16 + l15) * 64 + (((c*4 + quad) ^ l7) * 8);
    uint2* pw_ptr[2][4];
#pragma unroll
    for (int h = 0; h < 2; h++)
#pragma unroll
        for (int n = 0; n < 4; n++){
            int qloc = h * 16 + l15;
            int chunk = n * 2 + (quad >> 1);
            pw_ptr[h][n] = (uint2*)(P + qloc * 64 + ((chunk ^ l7) * 8) + (quad & 1) * 4);
        }
    // hoisted staging pointers, incremented by constants
    const unsigned short* kstage[4];
    const unsigned short* vstage[4];
    unsigned short* klds[4];
    unsigned short* vlds[4];
#pragma unroll
    for (int jj = 0; jj < 4; jj++){
        int rb = wid * 32 + jj * 8;
        kstage[jj] = Kp + (size_t)(rb + sr) * 64 + scl;
        vstage[jj] = Vp + (size_t)(rb + sr) * SEQ + scl;
        klds[jj] = &Ks[rb * 64];
        vlds[jj] = &Vs[rb * 64];
    }

    for (int kt = 0; kt < SEQ / 64; kt++){
        __syncthreads();
#pragma unroll
        for (int jj = 0; jj < 4; jj++){
            gload_lds16(kstage[jj], klds[jj]);
            gload_lds16(vstage[jj], vlds[jj]);
            kstage[jj] += 64 * 64;
            vstage[jj] += 64;
        }
        __syncthreads();

        // S^T: A = K-frag (rows kv), B = Q-frag
        f32x4 st[2][4];
#pragma unroll
        for (int n = 0; n < 4; n++){
            bf16x8 kf0 = *(const bf16x8*)kf_ptr[n][0];
            bf16x8 kf1 = *(const bf16x8*)kf_ptr[n][1];
#pragma unroll
            for (int h = 0; h < 2; h++){
                f32x4 z = __builtin_amdgcn_mfma_f32_16x16x32_bf16(kf0, qf[h][0], zz, 0, 0, 0);
                st[h][n] = __builtin_amdgcn_mfma_f32_16x16x32_bf16(kf1, qf[h][1], z, 0, 0, 0);
            }
        }

        // p = exp2(st); truncating pack to bf16; store 4 per ds_write_b64
#pragma unroll
        for (int h = 0; h < 2; h++){
#pragma unroll
            for (int n = 0; n < 4; n++){
                float p0 = __builtin_amdgcn_exp2f(st[h][n][0]);
                float p1 = __builtin_amdgcn_exp2f(st[h][n][1]);
                float p2 = __builtin_amdgcn_exp2f(st[h][n][2]);
                float p3 = __builtin_amdgcn_exp2f(st[h][n][3]);
                unsigned int w0 = __builtin_amdgcn_perm(asu(p1), asu(p0), 0x07060302u);
                unsigned int w1 = __builtin_amdgcn_perm(asu(p3), asu(p2), 0x07060302u);
                *pw_ptr[h][n] = make_uint2(w0, w1);
            }
        }

        asm volatile("s_waitcnt lgkmcnt(0)" ::: "memory");  // wave-private P w->r

        // O^T[d][q] += V^T * P^T; li via ones-MFMA
#pragma unroll
        for (int c = 0; c < 2; c++){
            bf16x8 pf[2];
#pragma unroll
            for (int h = 0; h < 2; h++)
                pf[h] = *(const bf16x8*)pf_ptr[c][h];
            sacc[0] = __builtin_amdgcn_mfma_f32_16x16x32_bf16(ones, pf[0], sacc[0], 0, 0, 0);
            sacc[1] = __builtin_amdgcn_mfma_f32_16x16x32_bf16(ones, pf[1], sacc[1], 0, 0, 0);
#pragma unroll
            for (int dn = 0; dn < 4; dn++){
                bf16x8 vf = *(const bf16x8*)vf_ptr[c][dn];
                oacc[0][dn] = __builtin_amdgcn_mfma_f32_16x16x32_bf16(vf, pf[0], oacc[0][dn], 0, 0, 0);
                oacc[1][dn] = __builtin_amdgcn_mfma_f32_16x16x32_bf16(vf, pf[1], oacc[1][dn], 0, 0, 0);
            }
        }
    }

    int b = bh / NHEAD, hh = bh - b * NHEAD;
#pragma unroll
    for (int h = 0; h < 2; h++){
        float rd = 1.0f / sacc[h][0];
        size_t row = (size_t)(b * SEQ + q0 + h*16 + l15);
#pragma unroll
        for (int dn = 0; dn < 4; dn++){
            float v0 = oacc[h][dn][0] * rd, v1 = oacc[h][dn][1] * rd;
            float v2 = oacc[h][dn][2] * rd, v3 = oacc[h][dn][3] * rd;
            unsigned int w0 = (unsigned int)f2bf(v0) | ((unsigned int)f2bf(v1) << 16);
            unsigned int w1 = (unsigned int)f2bf(v2) | ((unsigned int)f2bf(v3) << 16);
            *(uint2*)(O + row * DIM + hh * 64 + dn * 16 + quad * 4) = make_uint2(w0, w1);
        }
    }
}

// ---------------- launcher ----------------
extern "C" void kernel_launch(void* const* d_in, const int* in_sizes, int n_in,
                              void* d_out, int out_size, void* d_ws, size_t ws_size,
                              hipStream_t stream){
    const float* x      = (const float*)d_in[0];
    const float* ln1_g  = (const float*)d_in[1];
    const float* ln1_b  = (const float*)d_in[2];
    const float* qkv_w  = (const float*)d_in[3];
    const float* qkv_b  = (const float*)d_in[4];
    const float* proj_w = (const float*)d_in[5];
    const float* proj_b = (const float*)d_in[6];
    const float* ln2_g  = (const float*)d_in[7];
    const float* ln2_b  = (const float*)d_in[8];
    const float* fc1_w  = (const float*)d_in[9];
    const float* fc1_b  = (const float*)d_in[10];
    const float* fc2_w  = (const float*)d_in[11];
    const float* fc2_b  = (const float*)d_in[12];
    float* out = (float*)d_out;

    char* p = (char*)d_ws;
    auto take = [&](size_t n){ char* r = p; p += (n + 255) & ~(size_t)255; return r; };
    unsigned short* wt_qkv = (unsigned short*)take((size_t)1152 * 384 * 2);
    unsigned short* wt_prj = (unsigned short*)take((size_t)384 * 384 * 2);
    unsigned short* wt_fc1 = (unsigned short*)take((size_t)1536 * 384 * 2);
    unsigned short* wt_fc2 = (unsigned short*)take((size_t)384 * 1536 * 2);
    unsigned short* rbig   = (unsigned short*)take((size_t)MTOT * 4 * DIM * 2); // h1|q|k|v, later hm
    unsigned short* h2     = (unsigned short*)take((size_t)MTOT * DIM * 2);     // vtmp, later ln2-out
    float*          x1     = (float*)take((size_t)MTOT * DIM * 4);

    unsigned short* h1     = rbig;
    unsigned short* qb     = rbig + (size_t)MTOT * DIM;
    unsigned short* kb     = qb   + (size_t)MTOT * DIM;
    unsigned short* vb     = kb   + (size_t)MTOT * DIM;
    unsigned short* vtmp   = h2;     // dead before ln2 writes h2
    unsigned short* attn_o = rbig;   // reuses h1 (dead after QKV gemm)
    unsigned short* hm     = rbig;   // reuses h1+qkv (dead after proj)

    wt_all_kernel<<<dim3(432), 256, 0, stream>>>(qkv_w, proj_w, fc1_w, fc2_w,
                                                 wt_qkv, wt_prj, wt_fc1, wt_fc2);
    ln_kernel<<<dim3(MTOT/4), 256, 0, stream>>>(x, ln1_g, ln1_b, h1);
    gemm_kernel<0,128><<<dim3(9, 128), 256, 0, stream>>>(h1, wt_qkv, qkv_b, 384, 1152,
                                                         nullptr, nullptr, nullptr, qb, kb, vtmp);
    vt_kernel<<<dim3(SEQ/64, BATCH*NHEAD), 256, 0, stream>>>(vtmp, vb);
    attn_kernel<<<dim3(SEQ/64, BATCH*NHEAD), 128, 0, stream>>>(qb, kb, vb, attn_o);
    gemm_kernel<1,64><<<dim3(6, 128), 256, 0, stream>>>(attn_o, wt_prj, proj_b, 384, 384,
                                                        x, x1, nullptr, nullptr, nullptr, nullptr);
    ln_kernel<<<dim3(MTOT/4), 256, 0, stream>>>(x1, ln2_g, ln2_b, h2);
    gemm_kernel<2,128><<<dim3(12, 128), 256, 0, stream>>>(h2, wt_fc1, fc1_b, 384, 1536,
                                                          nullptr, nullptr, hm, nullptr, nullptr, nullptr);
    gemm_kernel<1,64><<<dim3(6, 128), 256, 0, stream>>>(hm, wt_fc2, fc2_b, 1536, 384,
                                                        x1, out, nullptr, nullptr, nullptr, nullptr);
}

// Round 7
// 328.124 us; speedup vs baseline: 1.3750x; 1.0042x over previous
//
#include <hip/hip_runtime.h>
#include <hip/hip_bf16.h>

#define DIM   384
#define SEQ   2048
#define BATCH 8
#define NHEAD 6
#define HD    64
#define MLPD  1536
#define MTOT  (BATCH*SEQ)   // 16384 rows

typedef __attribute__((ext_vector_type(8))) short bf16x8;
typedef __attribute__((ext_vector_type(4))) float f32x4;

static __device__ __forceinline__ float bf2f(unsigned short u){
    union { float f; unsigned int i; } v; v.i = ((unsigned int)u) << 16; return v.f;
}
static __device__ __forceinline__ unsigned short f2bf(float f){
    union { float f; unsigned int i; } v; v.f = f;
    unsigned int r = v.i + 0x7fffu + ((v.i >> 16) & 1u);
    return (unsigned short)(r >> 16);
}
static __device__ __forceinline__ unsigned int asu(float f){
    union { float f; unsigned int i; } v; v.f = f; return v.i;
}
// async global->LDS, 16B per lane; LDS dst = wave-uniform base + lane*16
static __device__ __forceinline__ void gload_lds16(const unsigned short* g, unsigned short* l){
    __builtin_amdgcn_global_load_lds(
        (__attribute__((address_space(1))) void*)(g),
        (__attribute__((address_space(3))) void*)(l), 16, 0, 0);
}

// ---------------- merged weight transpose + cast, LDS-tiled ----------------
__global__ __launch_bounds__(256) void wt_all_kernel(
    const float* __restrict__ qkv_w, const float* __restrict__ proj_w,
    const float* __restrict__ fc1_w, const float* __restrict__ fc2_w,
    unsigned short* __restrict__ o_qkv, unsigned short* __restrict__ o_prj,
    unsigned short* __restrict__ o_fc1, unsigned short* __restrict__ o_fc2)
{
    __shared__ float tile[64][68];
    int bid = blockIdx.x;
    const float* W; unsigned short* Wt; int K, N, tk, tn;
    if (bid < 108)      { W = qkv_w; Wt = o_qkv; K = 384;  N = 1152; tk = bid/18;        tn = bid%18; }
    else if (bid < 144) { W = proj_w; Wt = o_prj; K = 384;  N = 384;  tk = (bid-108)/6;  tn = (bid-108)%6; }
    else if (bid < 288) { W = fc1_w; Wt = o_fc1; K = 384;  N = 1536; tk = (bid-144)/24; tn = (bid-144)%24; }
    else                { W = fc2_w; Wt = o_fc2; K = 1536; N = 384;  tk = (bid-288)/6;  tn = (bid-288)%6; }
    int t = threadIdx.x;
    int lr = t >> 4, lc = (t & 15) * 4;
#pragma unroll
    for (int p = 0; p < 4; p++){
        float4 v = *(const float4*)(W + (size_t)(tk*64 + p*16 + lr) * N + tn*64 + lc);
        *(float4*)&tile[p*16 + lr][lc] = v;
    }
    __syncthreads();
    int n = t >> 2, k0 = (t & 3) * 16;
    unsigned int w[8];
#pragma unroll
    for (int i = 0; i < 8; i++)
        w[i] = (unsigned int)f2bf(tile[k0 + 2*i][n]) | ((unsigned int)f2bf(tile[k0 + 2*i + 1][n]) << 16);
    unsigned short* dst = Wt + (size_t)(tn*64 + n) * K + tk*64 + k0;
    *(uint4*)(dst)     = make_uint4(w[0], w[1], w[2], w[3]);
    *(uint4*)(dst + 8) = make_uint4(w[4], w[5], w[6], w[7]);
}

// ---------------- V transpose: vtmp [bh][ns][64] -> vb [bh][64][SEQ] ----------------
__global__ __launch_bounds__(256) void vt_kernel(const unsigned short* __restrict__ vtmp,
                                                 unsigned short* __restrict__ vb){
    __shared__ unsigned short tile[64][72];
    int bh = blockIdx.y, ns0 = blockIdx.x * 64;
    const unsigned short* src = vtmp + ((size_t)bh * SEQ + ns0) * 64;
    int t = threadIdx.x;
#pragma unroll
    for (int p = 0; p < 2; p++){
        int idx = t + p * 256;
        int r = idx >> 3, c = (idx & 7) * 8;
        *(uint4*)&tile[r][c] = *(const uint4*)(src + (size_t)r * 64 + c);
    }
    __syncthreads();
    int d = t >> 2, j0 = (t & 3) * 16;
    unsigned int w[8];
#pragma unroll
    for (int m = 0; m < 8; m++)
        w[m] = (unsigned int)tile[j0 + 2*m][d] | ((unsigned int)tile[j0 + 2*m + 1][d] << 16);
    unsigned short* dst = vb + ((size_t)bh * 64 + d) * SEQ + ns0 + j0;
    *(uint4*)(dst)     = make_uint4(w[0], w[1], w[2], w[3]);
    *(uint4*)(dst + 8) = make_uint4(w[4], w[5], w[6], w[7]);
}

// ---------------- layernorm: x f32 [rows][384] -> bf16 out ----------------
__global__ __launch_bounds__(256) void ln_kernel(const float* __restrict__ x,
                                                 const float* __restrict__ g,
                                                 const float* __restrict__ b,
                                                 unsigned short* __restrict__ out){
    int row  = blockIdx.x * 4 + (threadIdx.x >> 6);
    int lane = threadIdx.x & 63;
    const float* xr = x + (size_t)row * DIM;
    float v[6];
#pragma unroll
    for (int p = 0; p < 3; p++){
        float2 t = *(const float2*)(xr + lane * 2 + p * 128);
        v[2*p] = t.x; v[2*p+1] = t.y;
    }
    float s = 0.f, sq = 0.f;
#pragma unroll
    for (int i = 0; i < 6; i++){ s += v[i]; sq += v[i] * v[i]; }
#pragma unroll
    for (int off = 1; off < 64; off <<= 1){
        s  += __shfl_xor(s, off);
        sq += __shfl_xor(sq, off);
    }
    float mu   = s * (1.0f / DIM);
    float var  = sq * (1.0f / DIM) - mu * mu;
    float rstd = rsqrtf(var + 1e-5f);
    unsigned short* orow = out + (size_t)row * DIM;
#pragma unroll
    for (int p = 0; p < 3; p++){
        int c = lane * 2 + p * 128;
        float h0 = (v[2*p]   - mu) * rstd * g[c]   + b[c];
        float h1 = (v[2*p+1] - mu) * rstd * g[c+1] + b[c+1];
        unsigned int pk = (unsigned int)f2bf(h0) | ((unsigned int)f2bf(h1) << 16);
        *(unsigned int*)(orow + c) = pk;
    }
}

// ---------------- GEMM: C[M][N] = A[M][K] * Wt[N][K]^T, fused epilogues ----------------
// 2-stage LDS double-buffered pipeline: ONE __syncthreads per K-iter whose
// implicit vmcnt(0) drain covers EXACTLY tile i (tile i+1 is issued after the
// barrier) -> tile i+1's load latency hides behind tile i's compute.
// Buffer-reuse safe: tile i+1 targets the buffer last read at iter i-1; every
// wave's iter-(i-1) reads precede its iter-i barrier arrival.
template<int EPI, int BN>
__global__ __launch_bounds__(256) void gemm_kernel(
    const unsigned short* __restrict__ A, const unsigned short* __restrict__ Bt,
    const float* __restrict__ bias, int K, int N,
    const float* __restrict__ resid, float* __restrict__ outf,
    unsigned short* __restrict__ outb,
    unsigned short* __restrict__ qb, unsigned short* __restrict__ kb2,
    unsigned short* __restrict__ vb)
{
    constexpr int FI = (BN == 128) ? 4 : 2;
    constexpr int WROWS = (BN == 128) ? 64 : 32;
    __shared__ __align__(16) unsigned short As[2][128 * 64];
    __shared__ __align__(16) unsigned short Bs[2][BN * 64];
    int t = threadIdx.x;
    int wid = t >> 6, lane = t & 63, quad = lane >> 4, l15 = lane & 15;
    int wr = (BN == 128) ? (wid >> 1) : wid;
    int wc = (BN == 128) ? (wid & 1) : 0;
    int row0 = blockIdx.y * 128, col0 = blockIdx.x * BN;
    int sr = lane >> 3, sc = lane & 7;
    int scl = (sc ^ sr) * 8;                    // global-side swizzled chunk

    const unsigned short* Ab = A  + (size_t)row0 * K;
    const unsigned short* Bb = Bt + (size_t)col0 * K;

    f32x4 acc[FI][4];
    f32x4 zz = {0.f, 0.f, 0.f, 0.f};
#pragma unroll
    for (int i = 0; i < FI; i++)
#pragma unroll
        for (int j = 0; j < 4; j++) acc[i][j] = zz;

    auto issue = [&](int k0, int buf){
#pragma unroll
        for (int j = 0; j < 4; j++){
            int rb = wid * 32 + j * 8;
            gload_lds16(Ab + (size_t)(rb + sr) * K + k0 + scl, &As[buf][rb * 64]);
            if (BN == 128){
                gload_lds16(Bb + (size_t)(rb + sr) * K + k0 + scl, &Bs[buf][rb * 64]);
            } else if (j < 2){
                int rb2 = wid * 16 + j * 8;
                gload_lds16(Bb + (size_t)(rb2 + sr) * K + k0 + scl, &Bs[buf][rb2 * 64]);
            }
        }
    };

    issue(0, 0);
    int nk = K >> 6;
    for (int i = 0; i < nk; i++){
        __syncthreads();                        // drains vmcnt(0) == tile i ready
        if (i + 1 < nk) issue((i + 1) << 6, (i + 1) & 1);
        int cur = i & 1;
#pragma unroll
        for (int kk = 0; kk < 2; kk++){
            bf16x8 af[FI], bf[4];
#pragma unroll
            for (int ii = 0; ii < FI; ii++){
                int r = wr*WROWS + ii*16 + l15;
                af[ii] = *(const bf16x8*)&As[cur][r * 64 + (((kk*4 + quad) ^ (l15 & 7)) * 8)];
            }
#pragma unroll
            for (int j = 0; j < 4; j++){
                int r = wc*64 + j*16 + l15;
                bf[j] = *(const bf16x8*)&Bs[cur][r * 64 + (((kk*4 + quad) ^ (l15 & 7)) * 8)];
            }
#pragma unroll
            for (int ii = 0; ii < FI; ii++)
#pragma unroll
                for (int j = 0; j < 4; j++)
                    acc[ii][j] = __builtin_amdgcn_mfma_f32_16x16x32_bf16(af[ii], bf[j], acc[ii][j], 0, 0, 0);
        }
    }

#pragma unroll
    for (int i = 0; i < FI; i++){
#pragma unroll
        for (int j = 0; j < 4; j++){
            int gr0 = row0 + wr*WROWS + i*16 + quad*4;
            int gc  = col0 + wc*64 + j*16 + l15;
            float bia = bias[gc];
#pragma unroll
            for (int r = 0; r < 4; r++){
                int gr = gr0 + r;
                float val = acc[i][j][r] + bia;
                if (EPI == 1){
                    outf[(size_t)gr * N + gc] = resid[(size_t)gr * N + gc] + val;
                } else if (EPI == 2){
                    float u = val * (1.0f + 0.044715f * val * val);
                    float e = __builtin_amdgcn_exp2f(u * 2.3025851f);
                    outb[(size_t)gr * N + gc] = f2bf(val * e / (e + 1.0f));
                } else {
                    int trip = gc / 384, rem = gc - trip * 384;
                    int head = rem >> 6, d = rem & 63;
                    int bidx = gr >> 11, ns = gr & 2047;
                    size_t off = ((size_t)(bidx * NHEAD + head) * SEQ + ns) * 64 + d;
                    unsigned short* dst = (trip == 0) ? qb : (trip == 1) ? kb2 : vb;
                    dst[off] = f2bf(val);
                }
            }
        }
    }
}

// ---------------- flash attention v5 (unchanged from round 6) ----------------
__global__ __launch_bounds__(128, 3) void attn_kernel(const unsigned short* __restrict__ Q,
                                                      const unsigned short* __restrict__ Kb,
                                                      const unsigned short* __restrict__ Vt,
                                                      unsigned short* __restrict__ O){
    __shared__ __align__(16) unsigned short Ks[64 * 64];    // [kv][d], chunk-XOR swizzle
    __shared__ __align__(16) unsigned short Vs[64 * 64];    // [d][kv], same
    __shared__ __align__(16) unsigned short Ps[2][32 * 64]; // per-wave P [q][kv]

    int bh = blockIdx.y, qt = blockIdx.x;
    int t = threadIdx.x, wid = t >> 6, lane = t & 63, quad = lane >> 4, l15 = lane & 15;
    int l7 = l15 & 7;
    int q0 = qt * 64 + wid * 32;
    const unsigned short* Qp = Q  + (size_t)bh * SEQ * 64;
    const unsigned short* Kp = Kb + (size_t)bh * SEQ * 64;
    const unsigned short* Vp = Vt + (size_t)bh * 64 * SEQ;
    int sr = lane >> 3, sc = lane & 7;
    int scl = (sc ^ sr) * 8;

    const float QSCALE = 0.125f * 1.44269504f;  // fold 1/sqrt(64) and log2(e)
    bf16x8 qf[2][2];
#pragma unroll
    for (int h = 0; h < 2; h++){
#pragma unroll
        for (int c = 0; c < 2; c++){
            union { uint4 u; unsigned short s[8]; } cv;
            cv.u = *(const uint4*)(Qp + (size_t)(q0 + h*16 + l15) * 64 + c * 32 + quad * 8);
            bf16x8 f;
#pragma unroll
            for (int j = 0; j < 8; j++) f[j] = (short)f2bf(bf2f(cv.s[j]) * QSCALE);
            qf[h][c] = f;
        }
    }

    bf16x8 ones;
#pragma unroll
    for (int j = 0; j < 8; j++) ones[j] = (short)0x3F80;    // bf16 1.0

    f32x4 oacc[2][4], sacc[2];
    f32x4 zz = {0.f, 0.f, 0.f, 0.f};
#pragma unroll
    for (int h = 0; h < 2; h++){
        sacc[h] = zz;
#pragma unroll
        for (int dn = 0; dn < 4; dn++) oacc[h][dn] = zz;
    }
    unsigned short* P = &Ps[wid][0];

    // ---- hoisted LDS addresses (kt-invariant) ----
    const unsigned short* kf_ptr[4][2];
#pragma unroll
    for (int n = 0; n < 4; n++){
        int kv = n * 16 + l15;
        kf_ptr[n][0] = &Ks[kv * 64 + ((quad       ^ (kv & 7)) * 8)];
        kf_ptr[n][1] = &Ks[kv * 64 + (((4 + quad) ^ (kv & 7)) * 8)];
    }
    const unsigned short* vf_ptr[2][4];
#pragma unroll
    for (int c = 0; c < 2; c++)
#pragma unroll
        for (int dn = 0; dn < 4; dn++){
            int d = dn * 16 + l15;
            vf_ptr[c][dn] = &Vs[d * 64 + (((c*4 + quad) ^ (d & 7)) * 8)];
        }
    const unsigned short* pf_ptr[2][2];
#pragma unroll
    for (int c = 0; c < 2; c++)
#pragma unroll
        for (int h = 0; h < 2; h++)
            pf_ptr[c][h] = P + (h*16 + l15) * 64 + (((c*4 + quad) ^ l7) * 8);
    uint2* pw_ptr[2][4];
#pragma unroll
    for (int h = 0; h < 2; h++)
#pragma unroll
        for (int n = 0; n < 4; n++){
            int qloc = h * 16 + l15;
            int chunk = n * 2 + (quad >> 1);
            pw_ptr[h][n] = (uint2*)(P + qloc * 64 + ((chunk ^ l7) * 8) + (quad & 1) * 4);
        }
    const unsigned short* kstage[4];
    const unsigned short* vstage[4];
    unsigned short* klds[4];
    unsigned short* vlds[4];
#pragma unroll
    for (int jj = 0; jj < 4; jj++){
        int rb = wid * 32 + jj * 8;
        kstage[jj] = Kp + (size_t)(rb + sr) * 64 + scl;
        vstage[jj] = Vp + (size_t)(rb + sr) * SEQ + scl;
        klds[jj] = &Ks[rb * 64];
        vlds[jj] = &Vs[rb * 64];
    }

    for (int kt = 0; kt < SEQ / 64; kt++){
        __syncthreads();
#pragma unroll
        for (int jj = 0; jj < 4; jj++){
            gload_lds16(kstage[jj], klds[jj]);
            gload_lds16(vstage[jj], vlds[jj]);
            kstage[jj] += 64 * 64;
            vstage[jj] += 64;
        }
        __syncthreads();

        f32x4 st[2][4];
#pragma unroll
        for (int n = 0; n < 4; n++){
            bf16x8 kf0 = *(const bf16x8*)kf_ptr[n][0];
            bf16x8 kf1 = *(const bf16x8*)kf_ptr[n][1];
#pragma unroll
            for (int h = 0; h < 2; h++){
                f32x4 z = __builtin_amdgcn_mfma_f32_16x16x32_bf16(kf0, qf[h][0], zz, 0, 0, 0);
                st[h][n] = __builtin_amdgcn_mfma_f32_16x16x32_bf16(kf1, qf[h][1], z, 0, 0, 0);
            }
        }

#pragma unroll
        for (int h = 0; h < 2; h++){
#pragma unroll
            for (int n = 0; n < 4; n++){
                float p0 = __builtin_amdgcn_exp2f(st[h][n][0]);
                float p1 = __builtin_amdgcn_exp2f(st[h][n][1]);
                float p2 = __builtin_amdgcn_exp2f(st[h][n][2]);
                float p3 = __builtin_amdgcn_exp2f(st[h][n][3]);
                unsigned int w0 = __builtin_amdgcn_perm(asu(p1), asu(p0), 0x07060302u);
                unsigned int w1 = __builtin_amdgcn_perm(asu(p3), asu(p2), 0x07060302u);
                *pw_ptr[h][n] = make_uint2(w0, w1);
            }
        }

        asm volatile("s_waitcnt lgkmcnt(0)" ::: "memory");  // wave-private P w->r

#pragma unroll
        for (int c = 0; c < 2; c++){
            bf16x8 pf[2];
#pragma unroll
            for (int h = 0; h < 2; h++)
                pf[h] = *(const bf16x8*)pf_ptr[c][h];
            sacc[0] = __builtin_amdgcn_mfma_f32_16x16x32_bf16(ones, pf[0], sacc[0], 0, 0, 0);
            sacc[1] = __builtin_amdgcn_mfma_f32_16x16x32_bf16(ones, pf[1], sacc[1], 0, 0, 0);
#pragma unroll
            for (int dn = 0; dn < 4; dn++){
                bf16x8 vf = *(const bf16x8*)vf_ptr[c][dn];
                oacc[0][dn] = __builtin_amdgcn_mfma_f32_16x16x32_bf16(vf, pf[0], oacc[0][dn], 0, 0, 0);
                oacc[1][dn] = __builtin_amdgcn_mfma_f32_16x16x32_bf16(vf, pf[1], oacc[1][dn], 0, 0, 0);
            }
        }
    }

    int b = bh / NHEAD, hh = bh - b * NHEAD;
#pragma unroll
    for (int h = 0; h < 2; h++){
        float rd = 1.0f / sacc[h][0];
        size_t row = (size_t)(b * SEQ + q0 + h*16 + l15);
#pragma unroll
        for (int dn = 0; dn < 4; dn++){
            float v0 = oacc[h][dn][0] * rd, v1 = oacc[h][dn][1] * rd;
            float v2 = oacc[h][dn][2] * rd, v3 = oacc[h][dn][3] * rd;
            unsigned int w0 = (unsigned int)f2bf(v0) | ((unsigned int)f2bf(v1) << 16);
            unsigned int w1 = (unsigned int)f2bf(v2) | ((unsigned int)f2bf(v3) << 16);
            *(uint2*)(O + row * DIM + hh * 64 + dn * 16 + quad * 4) = make_uint2(w0, w1);
        }
    }
}

// ---------------- launcher ----------------
extern "C" void kernel_launch(void* const* d_in, const int* in_sizes, int n_in,
                              void* d_out, int out_size, void* d_ws, size_t ws_size,
                              hipStream_t stream){
    const float* x      = (const float*)d_in[0];
    const float* ln1_g  = (const float*)d_in[1];
    const float* ln1_b  = (const float*)d_in[2];
    const float* qkv_w  = (const float*)d_in[3];
    const float* qkv_b  = (const float*)d_in[4];
    const float* proj_w = (const float*)d_in[5];
    const float* proj_b = (const float*)d_in[6];
    const float* ln2_g  = (const float*)d_in[7];
    const float* ln2_b  = (const float*)d_in[8];
    const float* fc1_w  = (const float*)d_in[9];
    const float* fc1_b  = (const float*)d_in[10];
    const float* fc2_w  = (const float*)d_in[11];
    const float* fc2_b  = (const float*)d_in[12];
    float* out = (float*)d_out;

    char* p = (char*)d_ws;
    auto take = [&](size_t n){ char* r = p; p += (n + 255) & ~(size_t)255; return r; };
    unsigned short* wt_qkv = (unsigned short*)take((size_t)1152 * 384 * 2);
    unsigned short* wt_prj = (unsigned short*)take((size_t)384 * 384 * 2);
    unsigned short* wt_fc1 = (unsigned short*)take((size_t)1536 * 384 * 2);
    unsigned short* wt_fc2 = (unsigned short*)take((size_t)384 * 1536 * 2);
    unsigned short* rbig   = (unsigned short*)take((size_t)MTOT * 4 * DIM * 2); // h1|q|k|v, later hm
    unsigned short* h2     = (unsigned short*)take((size_t)MTOT * DIM * 2);     // vtmp, later ln2-out
    float*          x1     = (float*)take((size_t)MTOT * DIM * 4);

    unsigned short* h1     = rbig;
    unsigned short* qb     = rbig + (size_t)MTOT * DIM;
    unsigned short* kb     = qb   + (size_t)MTOT * DIM;
    unsigned short* vb     = kb   + (size_t)MTOT * DIM;
    unsigned short* vtmp   = h2;     // dead before ln2 writes h2
    unsigned short* attn_o = rbig;   // reuses h1 (dead after QKV gemm)
    unsigned short* hm     = rbig;   // reuses h1+qkv (dead after proj)

    wt_all_kernel<<<dim3(432), 256, 0, stream>>>(qkv_w, proj_w, fc1_w, fc2_w,
                                                 wt_qkv, wt_prj, wt_fc1, wt_fc2);
    ln_kernel<<<dim3(MTOT/4), 256, 0, stream>>>(x, ln1_g, ln1_b, h1);
    gemm_kernel<0,128><<<dim3(9, 128), 256, 0, stream>>>(h1, wt_qkv, qkv_b, 384, 1152,
                                                         nullptr, nullptr, nullptr, qb, kb, vtmp);
    vt_kernel<<<dim3(SEQ/64, BATCH*NHEAD), 256, 0, stream>>>(vtmp, vb);
    attn_kernel<<<dim3(SEQ/64, BATCH*NHEAD), 128, 0, stream>>>(qb, kb, vb, attn_o);
    gemm_kernel<1,64><<<dim3(6, 128), 256, 0, stream>>>(attn_o, wt_prj, proj_b, 384, 384,
                                                        x, x1, nullptr, nullptr, nullptr, nullptr);
    ln_kernel<<<dim3(MTOT/4), 256, 0, stream>>>(x1, ln2_g, ln2_b, h2);
    gemm_kernel<2,128><<<dim3(12, 128), 256, 0, stream>>>(h2, wt_fc1, fc1_b, 384, 1536,
                                                          nullptr, nullptr, hm, nullptr, nullptr, nullptr);
    gemm_kernel<1,64><<<dim3(6, 128), 256, 0, stream>>>(hm, wt_fc2, fc2_b, 1536, 384,
                                                        x1, out, nullptr, nullptr, nullptr, nullptr);
}

// Round 8
// 310.687 us; speedup vs baseline: 1.4522x; 1.0561x over previous
//
#include <hip/hip_runtime.h>
#include <hip/hip_bf16.h>

#define DIM   384
#define SEQ   2048
#define BATCH 8
#define NHEAD 6
#define HD    64
#define MLPD  1536
#define MTOT  (BATCH*SEQ)   // 16384 rows

typedef __attribute__((ext_vector_type(8))) short bf16x8;
typedef __attribute__((ext_vector_type(4))) float f32x4;

static __device__ __forceinline__ float bf2f(unsigned short u){
    union { float f; unsigned int i; } v; v.i = ((unsigned int)u) << 16; return v.f;
}
static __device__ __forceinline__ unsigned short f2bf(float f){
    union { float f; unsigned int i; } v; v.f = f;
    unsigned int r = v.i + 0x7fffu + ((v.i >> 16) & 1u);
    return (unsigned short)(r >> 16);
}
static __device__ __forceinline__ unsigned int asu(float f){
    union { float f; unsigned int i; } v; v.f = f; return v.i;
}
// async global->LDS, 16B per lane; LDS dst = wave-uniform base + lane*16
static __device__ __forceinline__ void gload_lds16(const unsigned short* g, unsigned short* l){
    __builtin_amdgcn_global_load_lds(
        (__attribute__((address_space(1))) void*)(g),
        (__attribute__((address_space(3))) void*)(l), 16, 0, 0);
}

// ---------------- merged weight transpose + cast, LDS-tiled ----------------
__global__ __launch_bounds__(256) void wt_all_kernel(
    const float* __restrict__ qkv_w, const float* __restrict__ proj_w,
    const float* __restrict__ fc1_w, const float* __restrict__ fc2_w,
    unsigned short* __restrict__ o_qkv, unsigned short* __restrict__ o_prj,
    unsigned short* __restrict__ o_fc1, unsigned short* __restrict__ o_fc2)
{
    __shared__ float tile[64][68];
    int bid = blockIdx.x;
    const float* W; unsigned short* Wt; int K, N, tk, tn;
    if (bid < 108)      { W = qkv_w; Wt = o_qkv; K = 384;  N = 1152; tk = bid/18;        tn = bid%18; }
    else if (bid < 144) { W = proj_w; Wt = o_prj; K = 384;  N = 384;  tk = (bid-108)/6;  tn = (bid-108)%6; }
    else if (bid < 288) { W = fc1_w; Wt = o_fc1; K = 384;  N = 1536; tk = (bid-144)/24; tn = (bid-144)%24; }
    else                { W = fc2_w; Wt = o_fc2; K = 1536; N = 384;  tk = (bid-288)/6;  tn = (bid-288)%6; }
    int t = threadIdx.x;
    int lr = t >> 4, lc = (t & 15) * 4;
#pragma unroll
    for (int p = 0; p < 4; p++){
        float4 v = *(const float4*)(W + (size_t)(tk*64 + p*16 + lr) * N + tn*64 + lc);
        *(float4*)&tile[p*16 + lr][lc] = v;
    }
    __syncthreads();
    int n = t >> 2, k0 = (t & 3) * 16;
    unsigned int w[8];
#pragma unroll
    for (int i = 0; i < 8; i++)
        w[i] = (unsigned int)f2bf(tile[k0 + 2*i][n]) | ((unsigned int)f2bf(tile[k0 + 2*i + 1][n]) << 16);
    unsigned short* dst = Wt + (size_t)(tn*64 + n) * K + tk*64 + k0;
    *(uint4*)(dst)     = make_uint4(w[0], w[1], w[2], w[3]);
    *(uint4*)(dst + 8) = make_uint4(w[4], w[5], w[6], w[7]);
}

// ---------------- layernorm: x f32 [rows][384] -> bf16 out ----------------
__global__ __launch_bounds__(256) void ln_kernel(const float* __restrict__ x,
                                                 const float* __restrict__ g,
                                                 const float* __restrict__ b,
                                                 unsigned short* __restrict__ out){
    int row  = blockIdx.x * 4 + (threadIdx.x >> 6);
    int lane = threadIdx.x & 63;
    const float* xr = x + (size_t)row * DIM;
    float v[6];
#pragma unroll
    for (int p = 0; p < 3; p++){
        float2 t = *(const float2*)(xr + lane * 2 + p * 128);
        v[2*p] = t.x; v[2*p+1] = t.y;
    }
    float s = 0.f, sq = 0.f;
#pragma unroll
    for (int i = 0; i < 6; i++){ s += v[i]; sq += v[i] * v[i]; }
#pragma unroll
    for (int off = 1; off < 64; off <<= 1){
        s  += __shfl_xor(s, off);
        sq += __shfl_xor(sq, off);
    }
    float mu   = s * (1.0f / DIM);
    float var  = sq * (1.0f / DIM) - mu * mu;
    float rstd = rsqrtf(var + 1e-5f);
    unsigned short* orow = out + (size_t)row * DIM;
#pragma unroll
    for (int p = 0; p < 3; p++){
        int c = lane * 2 + p * 128;
        float h0 = (v[2*p]   - mu) * rstd * g[c]   + b[c];
        float h1 = (v[2*p+1] - mu) * rstd * g[c+1] + b[c+1];
        unsigned int pk = (unsigned int)f2bf(h0) | ((unsigned int)f2bf(h1) << 16);
        *(unsigned int*)(orow + c) = pk;
    }
}

// ---------------- GEMM v2: 128-thread blocks, BM=64 x BN=128, single 24KB LDS ----------------
// 6 blocks/CU = 12 waves/CU (occupancy/TLP play for short-K latency hiding).
// EPI 0: qkv scatter; V col-blocks (col0>=768) transpose in-LDS -> vb [bh][64][SEQ]
// EPI 1: outf = resid + acc + bias (f32)
// EPI 2: outb = gelu(acc + bias) (bf16)
template<int EPI>
__global__ __launch_bounds__(128, 3) void gemm_kernel(
    const unsigned short* __restrict__ A, const unsigned short* __restrict__ Bt,
    const float* __restrict__ bias, int K, int N,
    const float* __restrict__ resid, float* __restrict__ outf,
    unsigned short* __restrict__ outb,
    unsigned short* __restrict__ qb, unsigned short* __restrict__ kb2,
    unsigned short* __restrict__ vb)
{
    __shared__ __align__(16) unsigned short smem[64*64 + 128*64]; // As(8K) | Bs(16K)
    unsigned short* As = smem;
    unsigned short* Bs = smem + 64*64;
    int t = threadIdx.x;
    int wid = t >> 6, lane = t & 63, quad = lane >> 4, l15 = lane & 15;
    int row0 = blockIdx.y * 64, col0 = blockIdx.x * 128;
    int sr = lane >> 3, sc = lane & 7;
    int scl = (sc ^ sr) * 8;                    // global-side swizzled chunk

    const unsigned short* Ab = A  + (size_t)row0 * K;
    const unsigned short* Bb = Bt + (size_t)col0 * K;

    f32x4 acc[2][8];
    f32x4 zz = {0.f, 0.f, 0.f, 0.f};
#pragma unroll
    for (int i = 0; i < 2; i++)
#pragma unroll
        for (int j = 0; j < 8; j++) acc[i][j] = zz;

    for (int k0 = 0; k0 < K; k0 += 64){
        __syncthreads();
#pragma unroll
        for (int jj = 0; jj < 4; jj++){          // A: 64 rows, wave wid stages rows wid*32..+32
            int rb = wid * 32 + jj * 8;
            gload_lds16(Ab + (size_t)(rb + sr) * K + k0 + scl, &As[rb * 64]);
        }
#pragma unroll
        for (int jj = 0; jj < 8; jj++){          // B: 128 rows, wave wid stages rows wid*64..+64
            int rb = wid * 64 + jj * 8;
            gload_lds16(Bb + (size_t)(rb + sr) * K + k0 + scl, &Bs[rb * 64]);
        }
        __syncthreads();                         // drains vmcnt(0): tile ready
#pragma unroll
        for (int kk = 0; kk < 2; kk++){
            bf16x8 af[2], bf[8];
#pragma unroll
            for (int i = 0; i < 2; i++){
                int r = wid*32 + i*16 + l15;
                af[i] = *(const bf16x8*)&As[r * 64 + (((kk*4 + quad) ^ (l15 & 7)) * 8)];
            }
#pragma unroll
            for (int j = 0; j < 8; j++){
                int r = j*16 + l15;
                bf[j] = *(const bf16x8*)&Bs[r * 64 + (((kk*4 + quad) ^ (l15 & 7)) * 8)];
            }
#pragma unroll
            for (int i = 0; i < 2; i++)
#pragma unroll
                for (int j = 0; j < 8; j++)
                    acc[i][j] = __builtin_amdgcn_mfma_f32_16x16x32_bf16(af[i], bf[j], acc[i][j], 0, 0, 0);
        }
    }

    if (EPI == 0 && col0 >= 768){
        // pure-V block: transpose 64(ns) x 128(d-cols) in LDS, write [d][ns] rows
        __syncthreads();                         // all frag reads done before aliasing smem
        unsigned short* T = smem;                // [128 gc_local][stride 72]
#pragma unroll
        for (int i = 0; i < 2; i++)
#pragma unroll
            for (int j = 0; j < 8; j++){
                int gcl = j*16 + l15;
                float bia = bias[col0 + gcl];
                int nsl0 = wid*32 + i*16 + quad*4;
#pragma unroll
                for (int r = 0; r < 4; r++)
                    T[gcl * 72 + nsl0 + r] = f2bf(acc[i][j][r] + bia);
            }
        __syncthreads();
        int rem = (col0 - 768) + t;              // t = gc_local 0..127
        int head = rem >> 6, d = rem & 63;
        int bidx = row0 >> 11, ns0 = row0 & 2047;
        unsigned short* dst = vb + ((size_t)((bidx * NHEAD + head) * 64 + d)) * SEQ + ns0;
        const unsigned short* src = T + t * 72;  // 144B stride, 16B-aligned
#pragma unroll
        for (int m = 0; m < 8; m++)
            *(uint4*)(dst + m*8) = *(const uint4*)(src + m*8);
        return;
    }

#pragma unroll
    for (int i = 0; i < 2; i++){
#pragma unroll
        for (int j = 0; j < 8; j++){
            int gr0 = row0 + wid*32 + i*16 + quad*4;
            int gc  = col0 + j*16 + l15;
            float bia = bias[gc];
#pragma unroll
            for (int r = 0; r < 4; r++){
                int gr = gr0 + r;
                float val = acc[i][j][r] + bia;
                if (EPI == 1){
                    outf[(size_t)gr * N + gc] = resid[(size_t)gr * N + gc] + val;
                } else if (EPI == 2){
                    float u = val * (1.0f + 0.044715f * val * val);
                    float e = __builtin_amdgcn_exp2f(u * 2.3025851f);
                    outb[(size_t)gr * N + gc] = f2bf(val * e / (e + 1.0f));
                } else {
                    int trip = gc / 384, remq = gc - trip * 384;
                    int head = remq >> 6, d = remq & 63;
                    int bidx = gr >> 11, ns = gr & 2047;
                    size_t off = ((size_t)(bidx * NHEAD + head) * SEQ + ns) * 64 + d;
                    unsigned short* dstp = (trip == 0) ? qb : kb2;
                    dstp[off] = f2bf(val);
                }
            }
        }
    }
}

// ---------------- flash attention v5 (unchanged control) ----------------
__global__ __launch_bounds__(128, 3) void attn_kernel(const unsigned short* __restrict__ Q,
                                                      const unsigned short* __restrict__ Kb,
                                                      const unsigned short* __restrict__ Vt,
                                                      unsigned short* __restrict__ O){
    __shared__ __align__(16) unsigned short Ks[64 * 64];    // [kv][d], chunk-XOR swizzle
    __shared__ __align__(16) unsigned short Vs[64 * 64];    // [d][kv], same
    __shared__ __align__(16) unsigned short Ps[2][32 * 64]; // per-wave P [q][kv]

    int bh = blockIdx.y, qt = blockIdx.x;
    int t = threadIdx.x, wid = t >> 6, lane = t & 63, quad = lane >> 4, l15 = lane & 15;
    int l7 = l15 & 7;
    int q0 = qt * 64 + wid * 32;
    const unsigned short* Qp = Q  + (size_t)bh * SEQ * 64;
    const unsigned short* Kp = Kb + (size_t)bh * SEQ * 64;
    const unsigned short* Vp = Vt + (size_t)bh * 64 * SEQ;
    int sr = lane >> 3, sc = lane & 7;
    int scl = (sc ^ sr) * 8;

    const float QSCALE = 0.125f * 1.44269504f;  // fold 1/sqrt(64) and log2(e)
    bf16x8 qf[2][2];
#pragma unroll
    for (int h = 0; h < 2; h++){
#pragma unroll
        for (int c = 0; c < 2; c++){
            union { uint4 u; unsigned short s[8]; } cv;
            cv.u = *(const uint4*)(Qp + (size_t)(q0 + h*16 + l15) * 64 + c * 32 + quad * 8);
            bf16x8 f;
#pragma unroll
            for (int j = 0; j < 8; j++) f[j] = (short)f2bf(bf2f(cv.s[j]) * QSCALE);
            qf[h][c] = f;
        }
    }

    bf16x8 ones;
#pragma unroll
    for (int j = 0; j < 8; j++) ones[j] = (short)0x3F80;    // bf16 1.0

    f32x4 oacc[2][4], sacc[2];
    f32x4 zz = {0.f, 0.f, 0.f, 0.f};
#pragma unroll
    for (int h = 0; h < 2; h++){
        sacc[h] = zz;
#pragma unroll
        for (int dn = 0; dn < 4; dn++) oacc[h][dn] = zz;
    }
    unsigned short* P = &Ps[wid][0];

    // ---- hoisted LDS addresses (kt-invariant) ----
    const unsigned short* kf_ptr[4][2];
#pragma unroll
    for (int n = 0; n < 4; n++){
        int kv = n * 16 + l15;
        kf_ptr[n][0] = &Ks[kv * 64 + ((quad       ^ (kv & 7)) * 8)];
        kf_ptr[n][1] = &Ks[kv * 64 + (((4 + quad) ^ (kv & 7)) * 8)];
    }
    const unsigned short* vf_ptr[2][4];
#pragma unroll
    for (int c = 0; c < 2; c++)
#pragma unroll
        for (int dn = 0; dn < 4; dn++){
            int d = dn * 16 + l15;
            vf_ptr[c][dn] = &Vs[d * 64 + (((c*4 + quad) ^ (d & 7)) * 8)];
        }
    const unsigned short* pf_ptr[2][2];
#pragma unroll
    for (int c = 0; c < 2; c++)
#pragma unroll
        for (int h = 0; h < 2; h++)
            pf_ptr[c][h] = P + (h*16 + l15) * 64 + (((c*4 + quad) ^ l7) * 8);
    uint2* pw_ptr[2][4];
#pragma unroll
    for (int h = 0; h < 2; h++)
#pragma unroll
        for (int n = 0; n < 4; n++){
            int qloc = h * 16 + l15;
            int chunk = n * 2 + (quad >> 1);
            pw_ptr[h][n] = (uint2*)(P + qloc * 64 + ((chunk ^ l7) * 8) + (quad & 1) * 4);
        }
    const unsigned short* kstage[4];
    const unsigned short* vstage[4];
    unsigned short* klds[4];
    unsigned short* vlds[4];
#pragma unroll
    for (int jj = 0; jj < 4; jj++){
        int rb = wid * 32 + jj * 8;
        kstage[jj] = Kp + (size_t)(rb + sr) * 64 + scl;
        vstage[jj] = Vp + (size_t)(rb + sr) * SEQ + scl;
        klds[jj] = &Ks[rb * 64];
        vlds[jj] = &Vs[rb * 64];
    }

    for (int kt = 0; kt < SEQ / 64; kt++){
        __syncthreads();
#pragma unroll
        for (int jj = 0; jj < 4; jj++){
            gload_lds16(kstage[jj], klds[jj]);
            gload_lds16(vstage[jj], vlds[jj]);
            kstage[jj] += 64 * 64;
            vstage[jj] += 64;
        }
        __syncthreads();

        f32x4 st[2][4];
#pragma unroll
        for (int n = 0; n < 4; n++){
            bf16x8 kf0 = *(const bf16x8*)kf_ptr[n][0];
            bf16x8 kf1 = *(const bf16x8*)kf_ptr[n][1];
#pragma unroll
            for (int h = 0; h < 2; h++){
                f32x4 z = __builtin_amdgcn_mfma_f32_16x16x32_bf16(kf0, qf[h][0], zz, 0, 0, 0);
                st[h][n] = __builtin_amdgcn_mfma_f32_16x16x32_bf16(kf1, qf[h][1], z, 0, 0, 0);
            }
        }

#pragma unroll
        for (int h = 0; h < 2; h++){
#pragma unroll
            for (int n = 0; n < 4; n++){
                float p0 = __builtin_amdgcn_exp2f(st[h][n][0]);
                float p1 = __builtin_amdgcn_exp2f(st[h][n][1]);
                float p2 = __builtin_amdgcn_exp2f(st[h][n][2]);
                float p3 = __builtin_amdgcn_exp2f(st[h][n][3]);
                unsigned int w0 = __builtin_amdgcn_perm(asu(p1), asu(p0), 0x07060302u);
                unsigned int w1 = __builtin_amdgcn_perm(asu(p3), asu(p2), 0x07060302u);
                *pw_ptr[h][n] = make_uint2(w0, w1);
            }
        }

        asm volatile("s_waitcnt lgkmcnt(0)" ::: "memory");  // wave-private P w->r

#pragma unroll
        for (int c = 0; c < 2; c++){
            bf16x8 pf[2];
#pragma unroll
            for (int h = 0; h < 2; h++)
                pf[h] = *(const bf16x8*)pf_ptr[c][h];
            sacc[0] = __builtin_amdgcn_mfma_f32_16x16x32_bf16(ones, pf[0], sacc[0], 0, 0, 0);
            sacc[1] = __builtin_amdgcn_mfma_f32_16x16x32_bf16(ones, pf[1], sacc[1], 0, 0, 0);
#pragma unroll
            for (int dn = 0; dn < 4; dn++){
                bf16x8 vf = *(const bf16x8*)vf_ptr[c][dn];
                oacc[0][dn] = __builtin_amdgcn_mfma_f32_16x16x32_bf16(vf, pf[0], oacc[0][dn], 0, 0, 0);
                oacc[1][dn] = __builtin_amdgcn_mfma_f32_16x16x32_bf16(vf, pf[1], oacc[1][dn], 0, 0, 0);
            }
        }
    }

    int b = bh / NHEAD, hh = bh - b * NHEAD;
#pragma unroll
    for (int h = 0; h < 2; h++){
        float rd = 1.0f / sacc[h][0];
        size_t row = (size_t)(b * SEQ + q0 + h*16 + l15);
#pragma unroll
        for (int dn = 0; dn < 4; dn++){
            float v0 = oacc[h][dn][0] * rd, v1 = oacc[h][dn][1] * rd;
            float v2 = oacc[h][dn][2] * rd, v3 = oacc[h][dn][3] * rd;
            unsigned int w0 = (unsigned int)f2bf(v0) | ((unsigned int)f2bf(v1) << 16);
            unsigned int w1 = (unsigned int)f2bf(v2) | ((unsigned int)f2bf(v3) << 16);
            *(uint2*)(O + row * DIM + hh * 64 + dn * 16 + quad * 4) = make_uint2(w0, w1);
        }
    }
}

// ---------------- launcher ----------------
extern "C" void kernel_launch(void* const* d_in, const int* in_sizes, int n_in,
                              void* d_out, int out_size, void* d_ws, size_t ws_size,
                              hipStream_t stream){
    const float* x      = (const float*)d_in[0];
    const float* ln1_g  = (const float*)d_in[1];
    const float* ln1_b  = (const float*)d_in[2];
    const float* qkv_w  = (const float*)d_in[3];
    const float* qkv_b  = (const float*)d_in[4];
    const float* proj_w = (const float*)d_in[5];
    const float* proj_b = (const float*)d_in[6];
    const float* ln2_g  = (const float*)d_in[7];
    const float* ln2_b  = (const float*)d_in[8];
    const float* fc1_w  = (const float*)d_in[9];
    const float* fc1_b  = (const float*)d_in[10];
    const float* fc2_w  = (const float*)d_in[11];
    const float* fc2_b  = (const float*)d_in[12];
    float* out = (float*)d_out;

    char* p = (char*)d_ws;
    auto take = [&](size_t n){ char* r = p; p += (n + 255) & ~(size_t)255; return r; };
    unsigned short* wt_qkv = (unsigned short*)take((size_t)1152 * 384 * 2);
    unsigned short* wt_prj = (unsigned short*)take((size_t)384 * 384 * 2);
    unsigned short* wt_fc1 = (unsigned short*)take((size_t)1536 * 384 * 2);
    unsigned short* wt_fc2 = (unsigned short*)take((size_t)384 * 1536 * 2);
    unsigned short* rbig   = (unsigned short*)take((size_t)MTOT * 4 * DIM * 2); // h1|q|k|v, later hm
    unsigned short* h2     = (unsigned short*)take((size_t)MTOT * DIM * 2);     // ln2 out
    float*          x1     = (float*)take((size_t)MTOT * DIM * 4);

    unsigned short* h1     = rbig;
    unsigned short* qb     = rbig + (size_t)MTOT * DIM;
    unsigned short* kb     = qb   + (size_t)MTOT * DIM;
    unsigned short* vb     = kb   + (size_t)MTOT * DIM;   // [bh][64][SEQ], written by qkv gemm
    unsigned short* attn_o = rbig;   // reuses h1 (dead after QKV gemm)
    unsigned short* hm     = rbig;   // reuses h1+qkv (dead after proj)

    wt_all_kernel<<<dim3(432), 256, 0, stream>>>(qkv_w, proj_w, fc1_w, fc2_w,
                                                 wt_qkv, wt_prj, wt_fc1, wt_fc2);
    ln_kernel<<<dim3(MTOT/4), 256, 0, stream>>>(x, ln1_g, ln1_b, h1);
    gemm_kernel<0><<<dim3(9, 256), 128, 0, stream>>>(h1, wt_qkv, qkv_b, 384, 1152,
                                                     nullptr, nullptr, nullptr, qb, kb, vb);
    attn_kernel<<<dim3(SEQ/64, BATCH*NHEAD), 128, 0, stream>>>(qb, kb, vb, attn_o);
    gemm_kernel<1><<<dim3(3, 256), 128, 0, stream>>>(attn_o, wt_prj, proj_b, 384, 384,
                                                     x, x1, nullptr, nullptr, nullptr, nullptr);
    ln_kernel<<<dim3(MTOT/4), 256, 0, stream>>>(x1, ln2_g, ln2_b, h2);
    gemm_kernel<2><<<dim3(12, 256), 128, 0, stream>>>(h2, wt_fc1, fc1_b, 384, 1536,
                                                      nullptr, nullptr, hm, nullptr, nullptr, nullptr);
    gemm_kernel<1><<<dim3(3, 256), 128, 0, stream>>>(hm, wt_fc2, fc2_b, 1536, 384,
                                                     x1, out, nullptr, nullptr, nullptr, nullptr);
}